// Round 8
// baseline (392.312 us; speedup 1.0000x reference)
//
#include <hip/hip_runtime.h>

#define NV 30000
#define MP 32

typedef short s16x8 __attribute__((ext_vector_type(8)));
typedef float f32x4 __attribute__((ext_vector_type(4)));

__device__ __forceinline__ unsigned short bf16h(float f) {
    unsigned int u = __float_as_uint(f);
    return (unsigned short)((u + 0x7FFFu + ((u >> 16) & 1u)) >> 16);
}
__device__ __forceinline__ float bf16f(unsigned short h) {
    return __uint_as_float(((unsigned int)h) << 16);
}
__device__ __forceinline__ unsigned int cvtpk(float a, float b) {
    unsigned int r;
    asm("v_cvt_pk_bf16_f32 %0, %1, %2" : "=v"(r) : "v"(a), "v"(b));
    return r;
}
// LDS write->read fence (intrinsic reads follow; no sched_barrier needed)
__device__ __forceinline__ void lgkm0() {
    asm volatile("s_waitcnt lgkmcnt(0)" ::: "memory");
}

// ---------------------------------------------------------------------------
// GEMM1: wave-per-voxel, fused voxstats, h1 via MFMA (bf16 3-pass).
// Grid 1875 x IT 4 x 4 waves = 30000 exact (no guards). No block barriers
// in main loop; per-voxel epilogue reduces ONLY mx/mn (sum/sumsq hoisted).
// ---------------------------------------------------------------------------
#define G1B 1875
#define G1IT 4
__global__ __launch_bounds__(256, 4) void k_gemm1(
    const float* __restrict__ feats, const int* __restrict__ npts,
    const int* __restrict__ coors, const float* __restrict__ W1,
    float* __restrict__ vstat,
    float* __restrict__ vmax1, float* __restrict__ vmin1,
    double* __restrict__ sum1, double* __restrict__ sumsq1)
{
    __shared__ unsigned short x1h[4][32*16], x1l[4][32*16];
    __shared__ float reds[4][64], redq[4][64];

    const int t = threadIdx.x, wave = t>>6, lane = t&63;
    const int lr = lane&15, g = lane>>4, m = lane&31;

    // W1 A-frags: A[ch][k], ch = ct*16+lr, k = g*8+j (k>=13 -> 0)
    s16x8 Wh[4], Wl[4];
    #pragma unroll
    for (int ct=0; ct<4; ++ct)
        #pragma unroll
        for (int j=0;j<8;++j) {
            int k = g*8 + j;
            float v = (k < 13) ? W1[k*64 + ct*16 + lr] : 0.f;
            unsigned short h = bf16h(v);
            Wh[ct][j] = (short)h; Wl[ct][j] = (short)bf16h(v - bf16f(h));
        }
    float accs[4][4], accq[4][4];
    #pragma unroll
    for (int ct=0;ct<4;++ct)
        #pragma unroll
        for (int r=0;r<4;++r) { accs[ct][r]=0.f; accq[ct][r]=0.f; }

    for (int it=0; it<G1IT; ++it) {
        const int v = (it*G1B + blockIdx.x)*4 + wave;   // < 30000 always
        if (lane < 32) {
            const int np = npts[v];
            const float fnp = (float)np;
            const float4 p = ((const float4*)feats)[(size_t)v*MP + m];
            const float msk = (m < np) ? 1.0f : 0.0f;
            float ux=p.x, uy=p.y, uz=p.z;
            float wx=p.x*msk, wy=p.y*msk, wz=p.z*msk;
            #pragma unroll
            for (int off=1; off<32; off<<=1) {
                ux += __shfl_xor(ux,off); uy += __shfl_xor(uy,off); uz += __shfl_xor(uz,off);
                wx += __shfl_xor(wx,off); wy += __shfl_xor(wy,off); wz += __shfl_xor(wz,off);
            }
            const float pmx=ux/fnp, pmy=uy/fnp, pmz=uz/fnp;
            const float vmx=wx/fnp, vmy=wy/fnp, vmz=wz/fnp;
            const float ddx=p.x-vmx, ddy=p.y-vmy, ddz=p.z-vmz;
            float d = sqrtf(ddx*ddx+ddy*ddy+ddz*ddz)*msk;
            #pragma unroll
            for (int off=1; off<32; off<<=1) d += __shfl_xor(d,off);
            const float md = d/fnp, dens = fnp/0.16f;
            if (m == 0) {
                float* o = vstat + (size_t)v*8;
                *(float4*)o       = make_float4(pmx,pmy,pmz,vmx);
                *(float4*)(o + 4) = make_float4(vmy,vmz,md,dens);
            }
            const float cx = (float)coors[v*4+3]*0.2f + 0.1f;
            const float cy = (float)coors[v*4+2]*0.2f - 39.9f;
            const float cz = (float)coors[v*4+1]*4.0f - 1.0f;
            float xv[16];
            xv[0]=p.x*msk; xv[1]=p.y*msk; xv[2]=p.z*msk; xv[3]=p.w*msk;
            xv[4]=(p.x-pmx)*msk; xv[5]=(p.y-pmy)*msk; xv[6]=(p.z-pmz)*msk;
            xv[7]=(p.x-cx)*msk; xv[8]=(p.y-cy)*msk; xv[9]=(p.z-cz)*msk;
            xv[10]=sqrtf(p.x*p.x+p.y*p.y+p.z*p.z)*msk;
            xv[11]=dens*msk; xv[12]=md*msk; xv[13]=0.f; xv[14]=0.f; xv[15]=0.f;
            unsigned int hu[8], lu[8];
            #pragma unroll
            for (int j=0;j<8;++j) {
                unsigned int hw = cvtpk(xv[2*j], xv[2*j+1]);
                float f0 = __uint_as_float(hw << 16);
                float f1 = __uint_as_float(hw & 0xffff0000u);
                lu[j] = cvtpk(xv[2*j]-f0, xv[2*j+1]-f1);
                hu[j] = hw;
            }
            const int base = m*16, sw = (m&7)<<3;
            *(uint4*)&x1h[wave][(base  ) ^ sw] = make_uint4(hu[0],hu[1],hu[2],hu[3]);
            *(uint4*)&x1h[wave][(base+8) ^ sw] = make_uint4(hu[4],hu[5],hu[6],hu[7]);
            *(uint4*)&x1l[wave][(base  ) ^ sw] = make_uint4(lu[0],lu[1],lu[2],lu[3]);
            *(uint4*)&x1l[wave][(base+8) ^ sw] = make_uint4(lu[4],lu[5],lu[6],lu[7]);
        }
        lgkm0();   // wave-private x1 RAW
        {
            const s16x8 zz = {0,0,0,0,0,0,0,0};
            s16x8 Bh[2], Bl[2];
            #pragma unroll
            for (int rg=0; rg<2; ++rg) {
                const int row = rg*16 + lr;
                if (g < 2) {
                    const int e = (row*16 + g*8) ^ ((row&7)<<3);
                    Bh[rg] = *(const s16x8*)&x1h[wave][e];
                    Bl[rg] = *(const s16x8*)&x1l[wave][e];
                } else { Bh[rg] = zz; Bl[rg] = zz; }
            }
            #pragma unroll
            for (int ct=0; ct<4; ++ct) {
                f32x4 h0; h0[0]=0.f;h0[1]=0.f;h0[2]=0.f;h0[3]=0.f;
                f32x4 h1v = h0;
                h0 = __builtin_amdgcn_mfma_f32_16x16x32_bf16(Wh[ct], Bh[0], h0, 0,0,0);
                h0 = __builtin_amdgcn_mfma_f32_16x16x32_bf16(Wl[ct], Bh[0], h0, 0,0,0);
                h0 = __builtin_amdgcn_mfma_f32_16x16x32_bf16(Wh[ct], Bl[0], h0, 0,0,0);
                h1v = __builtin_amdgcn_mfma_f32_16x16x32_bf16(Wh[ct], Bh[1], h1v, 0,0,0);
                h1v = __builtin_amdgcn_mfma_f32_16x16x32_bf16(Wl[ct], Bh[1], h1v, 0,0,0);
                h1v = __builtin_amdgcn_mfma_f32_16x16x32_bf16(Wh[ct], Bl[1], h1v, 0,0,0);
                float mxv[4], mnv[4];
                #pragma unroll
                for (int r=0;r<4;++r) {
                    accs[ct][r] += h0[r] + h1v[r];
                    accq[ct][r] = fmaf(h0[r],h0[r], fmaf(h1v[r],h1v[r], accq[ct][r]));
                    float mx = fmaxf(h0[r], h1v[r]), mn = fminf(h0[r], h1v[r]);
                    #pragma unroll
                    for (int off=1; off<16; off<<=1) {
                        mx = fmaxf(mx, __shfl_xor(mx,off));
                        mn = fminf(mn, __shfl_xor(mn,off));
                    }
                    mxv[r]=mx; mnv[r]=mn;
                }
                if (lr == 0) {
                    *(float4*)&vmax1[(size_t)v*64 + ct*16 + g*4] = make_float4(mxv[0],mxv[1],mxv[2],mxv[3]);
                    *(float4*)&vmin1[(size_t)v*64 + ct*16 + g*4] = make_float4(mnv[0],mnv[1],mnv[2],mnv[3]);
                }
            }
        }
    }
    // hoisted sum/sumsq reduction: butterfly over lr, then block + atomics
    #pragma unroll
    for (int ct=0;ct<4;++ct)
        #pragma unroll
        for (int r=0;r<4;++r) {
            float s = accs[ct][r], q = accq[ct][r];
            #pragma unroll
            for (int off=1; off<16; off<<=1) { s += __shfl_xor(s,off); q += __shfl_xor(q,off); }
            accs[ct][r]=s; accq[ct][r]=q;
        }
    if (lr == 0) {
        #pragma unroll
        for (int ct=0;ct<4;++ct) {
            *(float4*)&reds[wave][ct*16+g*4] = make_float4(accs[ct][0],accs[ct][1],accs[ct][2],accs[ct][3]);
            *(float4*)&redq[wave][ct*16+g*4] = make_float4(accq[ct][0],accq[ct][1],accq[ct][2],accq[ct][3]);
        }
    }
    __syncthreads();
    if (t < 64) {
        atomicAdd(&sum1[t],   (double)(reds[0][t]+reds[1][t]+reds[2][t]+reds[3][t]));
        atomicAdd(&sumsq1[t], (double)(redq[0][t]+redq[1][t]+redq[2][t]+redq[3][t]));
    }
}

__global__ void k_fin1(const double* __restrict__ sum1, const double* __restrict__ sumsq1,
                       const float* __restrict__ g1, const float* __restrict__ b1,
                       float* __restrict__ sc1, float* __restrict__ sh1) {
    int c = threadIdx.x;
    if (c >= 64) return;
    double cnt = (double)NV * MP;
    double mu = sum1[c]/cnt;
    double var = sumsq1[c]/cnt - mu*mu;
    double rs = 1.0 / sqrt(var + 1e-3);
    double sc = (double)g1[c]*rs;
    sc1[c] = (float)sc;
    sh1[c] = (float)((double)b1[c] - mu*sc);
}

// t[v][c] = agg[v][0:64] @ W2[64:128][c]; natural-layout w2s -> conflict-free
#define GAB 1875
__global__ __launch_bounds__(256) void k_aggt(
    const float* __restrict__ vmax1, const float* __restrict__ vmin1,
    const float* __restrict__ sc1, const float* __restrict__ sh1,
    const float* __restrict__ W2, float* __restrict__ tbuf)
{
    __shared__ float w2s[64][128];     // 32 KB, natural layout
    __shared__ float aggls[2][64];
    const int t = threadIdx.x;
    for (int i = t; i < 64*128; i += 256)
        ((float*)w2s)[i] = W2[64*128 + i];
    __syncthreads();
    const int v2 = t >> 7, c = t & 127;
    for (int it=0; it<8; ++it) {
        const int pair = it*GAB + blockIdx.x;   // < 15000 exact
        if (t < 128) {
            int vv = t >> 6, k = t & 63;
            float s = sc1[k];
            size_t o = (size_t)(pair*2+vv)*64 + k;
            float v = (s >= 0.f) ? vmax1[o] : vmin1[o];
            aggls[vv][k] = fmaxf(fmaf(v, s, sh1[k]), 0.f);
        }
        __syncthreads();
        float acc = 0.f;
        #pragma unroll 16
        for (int k=0; k<64; ++k)
            acc = fmaf(aggls[v2][k], w2s[k][c], acc);
        tbuf[(size_t)(pair*2+v2)*128 + c] = acc;
        __syncthreads();
    }
}

// ---------------------------------------------------------------------------
// GEMM2: 256 thr (4 waves), tile = 2 voxels (M=64) x N=128, K=64.
// Wave w: stages rows w*16+lr (g==0), computes h1^T for its rows (12 MFMA),
// then GEMM on N-slice w*32..+32 (48 MFMA). Grid 1875 x IT 8 = 15000 exact.
// LDS 20 KB; VGPR ~110 -> ~4 blocks/CU resident.
// ---------------------------------------------------------------------------
#define G2B 1875
#define G2IT 8
__global__ __launch_bounds__(256, 4) void k_gemm2(
    const float* __restrict__ feats, const int* __restrict__ npts,
    const int* __restrict__ coors, const float* __restrict__ vstat,
    const float* __restrict__ W1, const float* __restrict__ W2,
    const float* __restrict__ sc1, const float* __restrict__ sh1,
    const float* __restrict__ tbuf,
    float* __restrict__ vmax2, float* __restrict__ vmin2,
    double* __restrict__ sum2, double* __restrict__ sumsq2)
{
    __shared__ unsigned short x1h[64*16], x1l[64*16];   // 4 KB
    __shared__ unsigned short x2h[64*64], x2l[64*64];   // 16 KB

    const int t = threadIdx.x, w = t>>6, lane = t&63;
    const int lr = lane&15, g = lane>>4;

    // W2a B-frags (wave's 32-col slice)
    s16x8 Bh[2][2], Bl[2][2];
    {
        const int col0 = w*32 + lr;
        #pragma unroll
        for (int nt=0; nt<2; ++nt)
            #pragma unroll
            for (int ks=0; ks<2; ++ks)
                #pragma unroll
                for (int j=0; j<8; ++j) {
                    float v = W2[(ks*32 + g*8 + j)*128 + col0 + nt*16];
                    unsigned short h = bf16h(v);
                    Bh[nt][ks][j] = (short)h;
                    Bl[nt][ks][j] = (short)bf16h(v - bf16f(h));
                }
    }
    // W1' A-frags (sc1 folded), all 4 ct per wave
    s16x8 Wh[4], Wl[4];
    float shr[4][4];
    #pragma unroll
    for (int ct=0; ct<4; ++ct) {
        const int ch = ct*16 + lr;
        const float scv = sc1[ch];
        #pragma unroll
        for (int j=0; j<8; ++j) {
            int k = g*8 + j;
            float v = (k < 13) ? W1[k*64 + ch]*scv : 0.f;
            unsigned short h = bf16h(v);
            Wh[ct][j] = (short)h;
            Wl[ct][j] = (short)bf16h(v - bf16f(h));
        }
        #pragma unroll
        for (int r=0; r<4; ++r) shr[ct][r] = sh1[ct*16 + g*4 + r];
    }

    const int myrow = w*16 + lr;
    const int swx = (myrow&7) << 3;
    double dsum[2] = {0.0,0.0}, dsq[2] = {0.0,0.0};

    for (int it=0; it<G2IT; ++it) {
        const int pair = it*G2B + blockIdx.x;   // < 15000 exact
        const int vox0 = pair*2;
        float tvv[2][2];
        #pragma unroll
        for (int v=0; v<2; ++v)
            #pragma unroll
            for (int nt=0; nt<2; ++nt)
                tvv[v][nt] = tbuf[(size_t)(vox0+v)*128 + w*32 + nt*16 + lr];

        // ---- stage x1 (wave-private rows, g==0 lanes) ----
        if (g == 0) {
            const int vox = vox0 + (myrow >> 5);
            const int np = npts[vox];
            const float cx = (float)coors[vox*4+3]*0.2f + 0.1f;
            const float cy = (float)coors[vox*4+2]*0.2f - 39.9f;
            const float cz = (float)coors[vox*4+1]*4.0f - 1.0f;
            const float4 vsa = *(const float4*)&vstat[(size_t)vox*8];
            const float4 vsb = *(const float4*)&vstat[(size_t)vox*8+4];
            const int m = myrow & 31;
            const float4 p = ((const float4*)feats)[(size_t)vox*MP + m];
            const float msk = (m < np) ? 1.0f : 0.0f;
            float xv[16];
            xv[0]=p.x*msk; xv[1]=p.y*msk; xv[2]=p.z*msk; xv[3]=p.w*msk;
            xv[4]=(p.x-vsa.x)*msk; xv[5]=(p.y-vsa.y)*msk; xv[6]=(p.z-vsa.z)*msk;
            xv[7]=(p.x-cx)*msk; xv[8]=(p.y-cy)*msk; xv[9]=(p.z-cz)*msk;
            xv[10]=sqrtf(p.x*p.x+p.y*p.y+p.z*p.z)*msk;
            xv[11]=vsb.w*msk; xv[12]=vsb.z*msk; xv[13]=0.f; xv[14]=0.f; xv[15]=0.f;
            unsigned int hu[8], lu[8];
            #pragma unroll
            for (int j=0;j<8;++j) {
                unsigned int hw = cvtpk(xv[2*j], xv[2*j+1]);
                float f0 = __uint_as_float(hw << 16);
                float f1 = __uint_as_float(hw & 0xffff0000u);
                lu[j] = cvtpk(xv[2*j]-f0, xv[2*j+1]-f1);
                hu[j] = hw;
            }
            const int base = myrow*16;
            *(uint4*)&x1h[(base  ) ^ swx] = make_uint4(hu[0],hu[1],hu[2],hu[3]);
            *(uint4*)&x1h[(base+8) ^ swx] = make_uint4(hu[4],hu[5],hu[6],hu[7]);
            *(uint4*)&x1l[(base  ) ^ swx] = make_uint4(lu[0],lu[1],lu[2],lu[3]);
            *(uint4*)&x1l[(base+8) ^ swx] = make_uint4(lu[4],lu[5],lu[6],lu[7]);
        }
        lgkm0();   // wave-private x1 RAW

        // ---- h1 phase: wave's 16 rows x 64 ch -> x2 ----
        {
            const s16x8 zz = {0,0,0,0,0,0,0,0};
            s16x8 xh = zz, xl = zz;
            if (g < 2) {
                const int be = (myrow*16 + g*8) ^ swx;
                xh = *(const s16x8*)&x1h[be];
                xl = *(const s16x8*)&x1l[be];
            }
            #pragma unroll
            for (int ct=0; ct<4; ++ct) {
                f32x4 hv;
                hv[0]=shr[ct][0]; hv[1]=shr[ct][1]; hv[2]=shr[ct][2]; hv[3]=shr[ct][3];
                hv = __builtin_amdgcn_mfma_f32_16x16x32_bf16(Wh[ct], xh, hv, 0,0,0);
                hv = __builtin_amdgcn_mfma_f32_16x16x32_bf16(Wl[ct], xh, hv, 0,0,0);
                hv = __builtin_amdgcn_mfma_f32_16x16x32_bf16(Wh[ct], xl, hv, 0,0,0);
                float a0 = fmaxf(hv[0],0.f), a1 = fmaxf(hv[1],0.f);
                float a2 = fmaxf(hv[2],0.f), a3 = fmaxf(hv[3],0.f);
                unsigned int h01 = cvtpk(a0,a1), h23 = cvtpk(a2,a3);
                float r0 = a0 - __uint_as_float(h01<<16);
                float r1 = a1 - __uint_as_float(h01 & 0xffff0000u);
                float r2 = a2 - __uint_as_float(h23<<16);
                float r3 = a3 - __uint_as_float(h23 & 0xffff0000u);
                unsigned int l01 = cvtpk(r0,r1), l23 = cvtpk(r2,r3);
                const int e = (myrow*64 + ct*16 + g*4) ^ swx;
                *(uint2*)&x2h[e] = make_uint2(h01,h23);
                *(uint2*)&x2l[e] = make_uint2(l01,l23);
            }
        }
        __syncthreads();   // x2 ready for all waves

        // ---- GEMM2 MFMA: K=64, 3-pass ----
        f32x4 acc[4][2];
        #pragma unroll
        for (int mt=0;mt<4;++mt)
            #pragma unroll
            for (int nt=0;nt<2;++nt) {
                acc[mt][nt][0]=0.f; acc[mt][nt][1]=0.f;
                acc[mt][nt][2]=0.f; acc[mt][nt][3]=0.f;
            }
        #pragma unroll
        for (int ks=0; ks<2; ++ks) {
            s16x8 Ah[4], Al[4];
            #pragma unroll
            for (int mt=0;mt<4;++mt) {
                const int p = mt*16 + lr;
                const int e = (p*64 + ks*32 + g*8) ^ ((p&7)<<3);
                Ah[mt] = *(const s16x8*)&x2h[e];
                Al[mt] = *(const s16x8*)&x2l[e];
            }
            #pragma unroll
            for (int mt=0;mt<4;++mt)
                #pragma unroll
                for (int nt=0;nt<2;++nt) {
                    acc[mt][nt] = __builtin_amdgcn_mfma_f32_16x16x32_bf16(Ah[mt], Bh[nt][ks], acc[mt][nt], 0,0,0);
                    acc[mt][nt] = __builtin_amdgcn_mfma_f32_16x16x32_bf16(Al[mt], Bh[nt][ks], acc[mt][nt], 0,0,0);
                    acc[mt][nt] = __builtin_amdgcn_mfma_f32_16x16x32_bf16(Ah[mt], Bl[nt][ks], acc[mt][nt], 0,0,0);
                }
        }
        __syncthreads();   // reads done; next iter may overwrite

        // ---- epilogue: +t, per-voxel max/min, stats ----
        #pragma unroll
        for (int v=0; v<2; ++v) {
            #pragma unroll
            for (int nt=0; nt<2; ++nt) {
                const float tv = tvv[v][nt];
                const f32x4 qa = acc[2*v][nt], qb = acc[2*v+1][nt];
                float mx = fmaxf(fmaxf(fmaxf(qa[0],qa[1]), fmaxf(qa[2],qa[3])),
                                 fmaxf(fmaxf(qb[0],qb[1]), fmaxf(qb[2],qb[3])));
                float mn = fminf(fminf(fminf(qa[0],qa[1]), fminf(qa[2],qa[3])),
                                 fminf(fminf(qb[0],qb[1]), fminf(qb[2],qb[3])));
                mx = fmaxf(mx, __shfl_xor(mx,16)); mn = fminf(mn, __shfl_xor(mn,16));
                mx = fmaxf(mx, __shfl_xor(mx,32)); mn = fminf(mn, __shfl_xor(mn,32));
                if (lane < 16) {
                    const size_t o = (size_t)(vox0+v)*128 + w*32 + nt*16 + lr;
                    vmax2[o] = mx + tv; vmin2[o] = mn + tv;
                }
                float sl = 0.f, ql = 0.f;
                #pragma unroll
                for (int r=0;r<4;++r) {
                    float ea = qa[r] + tv, eb = qb[r] + tv;
                    sl += ea + eb;
                    ql = fmaf(ea,ea, fmaf(eb,eb, ql));
                }
                dsum[nt] += (double)sl; dsq[nt] += (double)ql;
            }
        }
    }
    #pragma unroll
    for (int nt=0; nt<2; ++nt) {
        double s = dsum[nt], q = dsq[nt];
        s += __shfl_xor(s,16); q += __shfl_xor(q,16);
        s += __shfl_xor(s,32); q += __shfl_xor(q,32);
        if (lane < 16) {
            atomicAdd(&sum2[w*32 + nt*16 + lr], s);
            atomicAdd(&sumsq2[w*32 + nt*16 + lr], q);
        }
    }
}

__global__ void k_fin2(const double* __restrict__ sum2, const double* __restrict__ sumsq2,
                       const float* __restrict__ g2, const float* __restrict__ b2,
                       float* __restrict__ sc2, float* __restrict__ sh2) {
    int c = threadIdx.x;
    if (c >= 128) return;
    double cnt = (double)NV * MP;
    double mu = sum2[c]/cnt;
    double var = sumsq2[c]/cnt - mu*mu;
    double rs = 1.0 / sqrt(var + 1e-3);
    double sc = (double)g2[c]*rs;
    sc2[c] = (float)sc;
    sh2[c] = (float)((double)b2[c] - mu*sc);
}

__global__ void k_out(const float* __restrict__ vmax2, const float* __restrict__ vmin2,
                      const float* __restrict__ sc2, const float* __restrict__ sh2,
                      float* __restrict__ out) {
    const int i = blockIdx.x*256 + threadIdx.x;   // < NV*32 exact
    const int c4 = (i & 31) << 2;
    const float4 mx = ((const float4*)vmax2)[i];
    const float4 mn = ((const float4*)vmin2)[i];
    const float4 sc = *(const float4*)&sc2[c4];
    const float4 sh = *(const float4*)&sh2[c4];
    float4 o;
    o.x = fmaxf(fmaf(sc.x>=0.f?mx.x:mn.x, sc.x, sh.x), 0.f);
    o.y = fmaxf(fmaf(sc.y>=0.f?mx.y:mn.y, sc.y, sh.y), 0.f);
    o.z = fmaxf(fmaf(sc.z>=0.f?mx.z:mn.z, sc.z, sh.z), 0.f);
    o.w = fmaxf(fmaf(sc.w>=0.f?mx.w:mn.w, sc.w, sh.w), 0.f);
    ((float4*)out)[i] = o;
}

extern "C" void kernel_launch(void* const* d_in, const int* in_sizes, int n_in,
                              void* d_out, int out_size, void* d_ws, size_t ws_size,
                              hipStream_t stream) {
    const float* feats = (const float*)d_in[0];
    const int*   npts  = (const int*)d_in[1];
    const int*   coors = (const int*)d_in[2];
    const float* W1    = (const float*)d_in[3];
    const float* g1    = (const float*)d_in[4];
    const float* b1    = (const float*)d_in[5];
    const float* W2    = (const float*)d_in[6];
    const float* g2    = (const float*)d_in[7];
    const float* b2    = (const float*)d_in[8];
    float* out = (float*)d_out;

    double* sum1   = (double*)d_ws;            // 64
    double* sumsq1 = sum1 + 64;                // 64
    double* sum2   = sumsq1 + 64;              // 128
    double* sumsq2 = sum2 + 128;               // 128 (384 doubles)
    float* fb = (float*)(sumsq2 + 128);
    float* vstat = fb;            fb += (size_t)NV*8;
    float* vmax1 = fb;            fb += (size_t)NV*64;
    float* vmin1 = fb;            fb += (size_t)NV*64;
    float* vmax2 = fb;            fb += (size_t)NV*128;
    float* vmin2 = fb;            fb += (size_t)NV*128;
    float* tbuf  = fb;            fb += (size_t)NV*128;
    float* sc1 = fb;              fb += 64;
    float* sh1 = fb;              fb += 64;
    float* sc2 = fb;              fb += 128;
    float* sh2 = fb;              fb += 128;

    hipMemsetAsync(d_ws, 0, 384*sizeof(double), stream);
    hipLaunchKernelGGL(k_gemm1, dim3(G1B), dim3(256), 0, stream,
                       feats, npts, coors, W1, vstat, vmax1, vmin1, sum1, sumsq1);
    hipLaunchKernelGGL(k_fin1, dim3(1), dim3(64), 0, stream,
                       sum1, sumsq1, g1, b1, sc1, sh1);
    hipLaunchKernelGGL(k_aggt, dim3(GAB), dim3(256), 0, stream,
                       vmax1, vmin1, sc1, sh1, W2, tbuf);
    hipLaunchKernelGGL(k_gemm2, dim3(G2B), dim3(256), 0, stream,
                       feats, npts, coors, vstat, W1, W2, sc1, sh1, tbuf,
                       vmax2, vmin2, sum2, sumsq2);
    hipLaunchKernelGGL(k_fin2, dim3(1), dim3(128), 0, stream,
                       sum2, sumsq2, g2, b2, sc2, sh2);
    hipLaunchKernelGGL(k_out, dim3(NV*32/256), dim3(256), 0, stream,
                       vmax2, vmin2, sc2, sh2, out);
}

// Round 9
// 330.343 us; speedup vs baseline: 1.1876x; 1.1876x over previous
//
#include <hip/hip_runtime.h>

#define NV 30000
#define MP 32

typedef short s16x8 __attribute__((ext_vector_type(8)));
typedef float f32x4 __attribute__((ext_vector_type(4)));

__device__ __forceinline__ unsigned short bf16h(float f) {
    unsigned int u = __float_as_uint(f);
    return (unsigned short)((u + 0x7FFFu + ((u >> 16) & 1u)) >> 16);
}
__device__ __forceinline__ float bf16f(unsigned short h) {
    return __uint_as_float(((unsigned int)h) << 16);
}
__device__ __forceinline__ unsigned int cvtpk(float a, float b) {
    unsigned int r;
    asm("v_cvt_pk_bf16_f32 %0, %1, %2" : "=v"(r) : "v"(a), "v"(b));
    return r;
}
// LDS write->read fence (intrinsic reads follow; no sched_barrier needed)
__device__ __forceinline__ void lgkm0() {
    asm volatile("s_waitcnt lgkmcnt(0)" ::: "memory");
}

// ---------------------------------------------------------------------------
// GEMM1: wave-per-voxel, fused voxstats, h1 via MFMA (bf16 3-pass).
// Grid 1875 x IT 4 x 4 waves = 30000 exact (no guards). No block barriers
// in main loop. launch_bounds(256,2): DO NOT raise min-waves — live-reg
// footprint ~150 VGPR; (256,4) caused 240 MB of spill traffic (R8).
// ---------------------------------------------------------------------------
#define G1B 1875
#define G1IT 4
__global__ __launch_bounds__(256, 2) void k_gemm1(
    const float* __restrict__ feats, const int* __restrict__ npts,
    const int* __restrict__ coors, const float* __restrict__ W1,
    float* __restrict__ vstat,
    float* __restrict__ vmax1, float* __restrict__ vmin1,
    double* __restrict__ sum1, double* __restrict__ sumsq1)
{
    __shared__ unsigned short x1h[4][32*16], x1l[4][32*16];
    __shared__ float reds[4][64], redq[4][64];

    const int t = threadIdx.x, wave = t>>6, lane = t&63;
    const int lr = lane&15, g = lane>>4, m = lane&31;

    // W1 A-frags: A[ch][k], ch = ct*16+lr, k = g*8+j (k>=13 -> 0)
    s16x8 Wh[4], Wl[4];
    #pragma unroll
    for (int ct=0; ct<4; ++ct)
        #pragma unroll
        for (int j=0;j<8;++j) {
            int k = g*8 + j;
            float v = (k < 13) ? W1[k*64 + ct*16 + lr] : 0.f;
            unsigned short h = bf16h(v);
            Wh[ct][j] = (short)h; Wl[ct][j] = (short)bf16h(v - bf16f(h));
        }
    float accs[4][4], accq[4][4];
    #pragma unroll
    for (int ct=0;ct<4;++ct)
        #pragma unroll
        for (int r=0;r<4;++r) { accs[ct][r]=0.f; accq[ct][r]=0.f; }

    for (int it=0; it<G1IT; ++it) {
        const int v = (it*G1B + blockIdx.x)*4 + wave;   // < 30000 always
        if (lane < 32) {
            const int np = npts[v];
            const float fnp = (float)np;
            const float4 p = ((const float4*)feats)[(size_t)v*MP + m];
            const float msk = (m < np) ? 1.0f : 0.0f;
            float ux=p.x, uy=p.y, uz=p.z;
            float wx=p.x*msk, wy=p.y*msk, wz=p.z*msk;
            #pragma unroll
            for (int off=1; off<32; off<<=1) {
                ux += __shfl_xor(ux,off); uy += __shfl_xor(uy,off); uz += __shfl_xor(uz,off);
                wx += __shfl_xor(wx,off); wy += __shfl_xor(wy,off); wz += __shfl_xor(wz,off);
            }
            const float pmx=ux/fnp, pmy=uy/fnp, pmz=uz/fnp;
            const float vmx=wx/fnp, vmy=wy/fnp, vmz=wz/fnp;
            const float ddx=p.x-vmx, ddy=p.y-vmy, ddz=p.z-vmz;
            float d = sqrtf(ddx*ddx+ddy*ddy+ddz*ddz)*msk;
            #pragma unroll
            for (int off=1; off<32; off<<=1) d += __shfl_xor(d,off);
            const float md = d/fnp, dens = fnp/0.16f;
            if (m == 0) {
                float* o = vstat + (size_t)v*8;
                *(float4*)o       = make_float4(pmx,pmy,pmz,vmx);
                *(float4*)(o + 4) = make_float4(vmy,vmz,md,dens);
            }
            const float cx = (float)coors[v*4+3]*0.2f + 0.1f;
            const float cy = (float)coors[v*4+2]*0.2f - 39.9f;
            const float cz = (float)coors[v*4+1]*4.0f - 1.0f;
            float xv[16];
            xv[0]=p.x*msk; xv[1]=p.y*msk; xv[2]=p.z*msk; xv[3]=p.w*msk;
            xv[4]=(p.x-pmx)*msk; xv[5]=(p.y-pmy)*msk; xv[6]=(p.z-pmz)*msk;
            xv[7]=(p.x-cx)*msk; xv[8]=(p.y-cy)*msk; xv[9]=(p.z-cz)*msk;
            xv[10]=sqrtf(p.x*p.x+p.y*p.y+p.z*p.z)*msk;
            xv[11]=dens*msk; xv[12]=md*msk; xv[13]=0.f; xv[14]=0.f; xv[15]=0.f;
            unsigned int hu[8], lu[8];
            #pragma unroll
            for (int j=0;j<8;++j) {
                unsigned int hw = cvtpk(xv[2*j], xv[2*j+1]);
                float f0 = __uint_as_float(hw << 16);
                float f1 = __uint_as_float(hw & 0xffff0000u);
                lu[j] = cvtpk(xv[2*j]-f0, xv[2*j+1]-f1);
                hu[j] = hw;
            }
            const int base = m*16, sw = (m&7)<<3;
            *(uint4*)&x1h[wave][(base  ) ^ sw] = make_uint4(hu[0],hu[1],hu[2],hu[3]);
            *(uint4*)&x1h[wave][(base+8) ^ sw] = make_uint4(hu[4],hu[5],hu[6],hu[7]);
            *(uint4*)&x1l[wave][(base  ) ^ sw] = make_uint4(lu[0],lu[1],lu[2],lu[3]);
            *(uint4*)&x1l[wave][(base+8) ^ sw] = make_uint4(lu[4],lu[5],lu[6],lu[7]);
        }
        lgkm0();   // wave-private x1 RAW
        {
            const s16x8 zz = {0,0,0,0,0,0,0,0};
            s16x8 Bh[2], Bl[2];
            #pragma unroll
            for (int rg=0; rg<2; ++rg) {
                const int row = rg*16 + lr;
                if (g < 2) {
                    const int e = (row*16 + g*8) ^ ((row&7)<<3);
                    Bh[rg] = *(const s16x8*)&x1h[wave][e];
                    Bl[rg] = *(const s16x8*)&x1l[wave][e];
                } else { Bh[rg] = zz; Bl[rg] = zz; }
            }
            #pragma unroll
            for (int ct=0; ct<4; ++ct) {
                f32x4 h0; h0[0]=0.f;h0[1]=0.f;h0[2]=0.f;h0[3]=0.f;
                f32x4 h1v = h0;
                h0 = __builtin_amdgcn_mfma_f32_16x16x32_bf16(Wh[ct], Bh[0], h0, 0,0,0);
                h0 = __builtin_amdgcn_mfma_f32_16x16x32_bf16(Wl[ct], Bh[0], h0, 0,0,0);
                h0 = __builtin_amdgcn_mfma_f32_16x16x32_bf16(Wh[ct], Bl[0], h0, 0,0,0);
                h1v = __builtin_amdgcn_mfma_f32_16x16x32_bf16(Wh[ct], Bh[1], h1v, 0,0,0);
                h1v = __builtin_amdgcn_mfma_f32_16x16x32_bf16(Wl[ct], Bh[1], h1v, 0,0,0);
                h1v = __builtin_amdgcn_mfma_f32_16x16x32_bf16(Wh[ct], Bl[1], h1v, 0,0,0);
                float mxv[4], mnv[4];
                #pragma unroll
                for (int r=0;r<4;++r) {
                    accs[ct][r] += h0[r] + h1v[r];
                    accq[ct][r] = fmaf(h0[r],h0[r], fmaf(h1v[r],h1v[r], accq[ct][r]));
                    float mx = fmaxf(h0[r], h1v[r]), mn = fminf(h0[r], h1v[r]);
                    #pragma unroll
                    for (int off=1; off<16; off<<=1) {
                        mx = fmaxf(mx, __shfl_xor(mx,off));
                        mn = fminf(mn, __shfl_xor(mn,off));
                    }
                    mxv[r]=mx; mnv[r]=mn;
                }
                if (lr == 0) {
                    *(float4*)&vmax1[(size_t)v*64 + ct*16 + g*4] = make_float4(mxv[0],mxv[1],mxv[2],mxv[3]);
                    *(float4*)&vmin1[(size_t)v*64 + ct*16 + g*4] = make_float4(mnv[0],mnv[1],mnv[2],mnv[3]);
                }
            }
        }
    }
    // hoisted sum/sumsq reduction: butterfly over lr, then block + atomics
    #pragma unroll
    for (int ct=0;ct<4;++ct)
        #pragma unroll
        for (int r=0;r<4;++r) {
            float s = accs[ct][r], q = accq[ct][r];
            #pragma unroll
            for (int off=1; off<16; off<<=1) { s += __shfl_xor(s,off); q += __shfl_xor(q,off); }
            accs[ct][r]=s; accq[ct][r]=q;
        }
    if (lr == 0) {
        #pragma unroll
        for (int ct=0;ct<4;++ct) {
            *(float4*)&reds[wave][ct*16+g*4] = make_float4(accs[ct][0],accs[ct][1],accs[ct][2],accs[ct][3]);
            *(float4*)&redq[wave][ct*16+g*4] = make_float4(accq[ct][0],accq[ct][1],accq[ct][2],accq[ct][3]);
        }
    }
    __syncthreads();
    if (t < 64) {
        atomicAdd(&sum1[t],   (double)(reds[0][t]+reds[1][t]+reds[2][t]+reds[3][t]));
        atomicAdd(&sumsq1[t], (double)(redq[0][t]+redq[1][t]+redq[2][t]+redq[3][t]));
    }
}

__global__ void k_fin1(const double* __restrict__ sum1, const double* __restrict__ sumsq1,
                       const float* __restrict__ g1, const float* __restrict__ b1,
                       float* __restrict__ sc1, float* __restrict__ sh1) {
    int c = threadIdx.x;
    if (c >= 64) return;
    double cnt = (double)NV * MP;
    double mu = sum1[c]/cnt;
    double var = sumsq1[c]/cnt - mu*mu;
    double rs = 1.0 / sqrt(var + 1e-3);
    double sc = (double)g1[c]*rs;
    sc1[c] = (float)sc;
    sh1[c] = (float)((double)b1[c] - mu*sc);
}

// t[v][c] = agg[v][0:64] @ W2[64:128][c]; natural-layout w2s -> conflict-free
#define GAB 1875
__global__ __launch_bounds__(256) void k_aggt(
    const float* __restrict__ vmax1, const float* __restrict__ vmin1,
    const float* __restrict__ sc1, const float* __restrict__ sh1,
    const float* __restrict__ W2, float* __restrict__ tbuf)
{
    __shared__ float w2s[64][128];     // 32 KB, natural layout
    __shared__ float aggls[2][64];
    const int t = threadIdx.x;
    for (int i = t; i < 64*128; i += 256)
        ((float*)w2s)[i] = W2[64*128 + i];
    __syncthreads();
    const int v2 = t >> 7, c = t & 127;
    for (int it=0; it<8; ++it) {
        const int pair = it*GAB + blockIdx.x;   // < 15000 exact
        if (t < 128) {
            int vv = t >> 6, k = t & 63;
            float s = sc1[k];
            size_t o = (size_t)(pair*2+vv)*64 + k;
            float v = (s >= 0.f) ? vmax1[o] : vmin1[o];
            aggls[vv][k] = fmaxf(fmaf(v, s, sh1[k]), 0.f);
        }
        __syncthreads();
        float acc = 0.f;
        #pragma unroll 16
        for (int k=0; k<64; ++k)
            acc = fmaf(aggls[v2][k], w2s[k][c], acc);
        tbuf[(size_t)(pair*2+v2)*128 + c] = acc;
        __syncthreads();
    }
}

// ---------------------------------------------------------------------------
// GEMM2: 256 thr (4 waves), tile = 2 voxels (M=64) x N=128, K=64.
// Wave w: stages rows w*16+lr (g==0), computes h1^T for its rows (12 MFMA),
// then GEMM on N-slice w*32..+32 (48 MFMA). Grid 1875 x IT 8 = 15000 exact.
// launch_bounds(256,2): see k_gemm1 comment — (256,4) spills catastrophically.
// ---------------------------------------------------------------------------
#define G2B 1875
#define G2IT 8
__global__ __launch_bounds__(256, 2) void k_gemm2(
    const float* __restrict__ feats, const int* __restrict__ npts,
    const int* __restrict__ coors, const float* __restrict__ vstat,
    const float* __restrict__ W1, const float* __restrict__ W2,
    const float* __restrict__ sc1, const float* __restrict__ sh1,
    const float* __restrict__ tbuf,
    float* __restrict__ vmax2, float* __restrict__ vmin2,
    double* __restrict__ sum2, double* __restrict__ sumsq2)
{
    __shared__ unsigned short x1h[64*16], x1l[64*16];   // 4 KB
    __shared__ unsigned short x2h[64*64], x2l[64*64];   // 16 KB

    const int t = threadIdx.x, w = t>>6, lane = t&63;
    const int lr = lane&15, g = lane>>4;

    // W2a B-frags (wave's 32-col slice)
    s16x8 Bh[2][2], Bl[2][2];
    {
        const int col0 = w*32 + lr;
        #pragma unroll
        for (int nt=0; nt<2; ++nt)
            #pragma unroll
            for (int ks=0; ks<2; ++ks)
                #pragma unroll
                for (int j=0; j<8; ++j) {
                    float v = W2[(ks*32 + g*8 + j)*128 + col0 + nt*16];
                    unsigned short h = bf16h(v);
                    Bh[nt][ks][j] = (short)h;
                    Bl[nt][ks][j] = (short)bf16h(v - bf16f(h));
                }
    }
    // W1' A-frags (sc1 folded), all 4 ct per wave
    s16x8 Wh[4], Wl[4];
    float shr[4][4];
    #pragma unroll
    for (int ct=0; ct<4; ++ct) {
        const int ch = ct*16 + lr;
        const float scv = sc1[ch];
        #pragma unroll
        for (int j=0; j<8; ++j) {
            int k = g*8 + j;
            float v = (k < 13) ? W1[k*64 + ch]*scv : 0.f;
            unsigned short h = bf16h(v);
            Wh[ct][j] = (short)h;
            Wl[ct][j] = (short)bf16h(v - bf16f(h));
        }
        #pragma unroll
        for (int r=0; r<4; ++r) shr[ct][r] = sh1[ct*16 + g*4 + r];
    }

    const int myrow = w*16 + lr;
    const int swx = (myrow&7) << 3;
    double dsum[2] = {0.0,0.0}, dsq[2] = {0.0,0.0};

    for (int it=0; it<G2IT; ++it) {
        const int pair = it*G2B + blockIdx.x;   // < 15000 exact
        const int vox0 = pair*2;
        float tvv[2][2];
        #pragma unroll
        for (int v=0; v<2; ++v)
            #pragma unroll
            for (int nt=0; nt<2; ++nt)
                tvv[v][nt] = tbuf[(size_t)(vox0+v)*128 + w*32 + nt*16 + lr];

        // ---- stage x1 (wave-private rows, g==0 lanes) ----
        if (g == 0) {
            const int vox = vox0 + (myrow >> 5);
            const int np = npts[vox];
            const float cx = (float)coors[vox*4+3]*0.2f + 0.1f;
            const float cy = (float)coors[vox*4+2]*0.2f - 39.9f;
            const float cz = (float)coors[vox*4+1]*4.0f - 1.0f;
            const float4 vsa = *(const float4*)&vstat[(size_t)vox*8];
            const float4 vsb = *(const float4*)&vstat[(size_t)vox*8+4];
            const int m = myrow & 31;
            const float4 p = ((const float4*)feats)[(size_t)vox*MP + m];
            const float msk = (m < np) ? 1.0f : 0.0f;
            float xv[16];
            xv[0]=p.x*msk; xv[1]=p.y*msk; xv[2]=p.z*msk; xv[3]=p.w*msk;
            xv[4]=(p.x-vsa.x)*msk; xv[5]=(p.y-vsa.y)*msk; xv[6]=(p.z-vsa.z)*msk;
            xv[7]=(p.x-cx)*msk; xv[8]=(p.y-cy)*msk; xv[9]=(p.z-cz)*msk;
            xv[10]=sqrtf(p.x*p.x+p.y*p.y+p.z*p.z)*msk;
            xv[11]=vsb.w*msk; xv[12]=vsb.z*msk; xv[13]=0.f; xv[14]=0.f; xv[15]=0.f;
            unsigned int hu[8], lu[8];
            #pragma unroll
            for (int j=0;j<8;++j) {
                unsigned int hw = cvtpk(xv[2*j], xv[2*j+1]);
                float f0 = __uint_as_float(hw << 16);
                float f1 = __uint_as_float(hw & 0xffff0000u);
                lu[j] = cvtpk(xv[2*j]-f0, xv[2*j+1]-f1);
                hu[j] = hw;
            }
            const int base = myrow*16;
            *(uint4*)&x1h[(base  ) ^ swx] = make_uint4(hu[0],hu[1],hu[2],hu[3]);
            *(uint4*)&x1h[(base+8) ^ swx] = make_uint4(hu[4],hu[5],hu[6],hu[7]);
            *(uint4*)&x1l[(base  ) ^ swx] = make_uint4(lu[0],lu[1],lu[2],lu[3]);
            *(uint4*)&x1l[(base+8) ^ swx] = make_uint4(lu[4],lu[5],lu[6],lu[7]);
        }
        lgkm0();   // wave-private x1 RAW

        // ---- h1 phase: wave's 16 rows x 64 ch -> x2 ----
        {
            const s16x8 zz = {0,0,0,0,0,0,0,0};
            s16x8 xh = zz, xl = zz;
            if (g < 2) {
                const int be = (myrow*16 + g*8) ^ swx;
                xh = *(const s16x8*)&x1h[be];
                xl = *(const s16x8*)&x1l[be];
            }
            #pragma unroll
            for (int ct=0; ct<4; ++ct) {
                f32x4 hv;
                hv[0]=shr[ct][0]; hv[1]=shr[ct][1]; hv[2]=shr[ct][2]; hv[3]=shr[ct][3];
                hv = __builtin_amdgcn_mfma_f32_16x16x32_bf16(Wh[ct], xh, hv, 0,0,0);
                hv = __builtin_amdgcn_mfma_f32_16x16x32_bf16(Wl[ct], xh, hv, 0,0,0);
                hv = __builtin_amdgcn_mfma_f32_16x16x32_bf16(Wh[ct], xl, hv, 0,0,0);
                float a0 = fmaxf(hv[0],0.f), a1 = fmaxf(hv[1],0.f);
                float a2 = fmaxf(hv[2],0.f), a3 = fmaxf(hv[3],0.f);
                unsigned int h01 = cvtpk(a0,a1), h23 = cvtpk(a2,a3);
                float r0 = a0 - __uint_as_float(h01<<16);
                float r1 = a1 - __uint_as_float(h01 & 0xffff0000u);
                float r2 = a2 - __uint_as_float(h23<<16);
                float r3 = a3 - __uint_as_float(h23 & 0xffff0000u);
                unsigned int l01 = cvtpk(r0,r1), l23 = cvtpk(r2,r3);
                const int e = (myrow*64 + ct*16 + g*4) ^ swx;
                *(uint2*)&x2h[e] = make_uint2(h01,h23);
                *(uint2*)&x2l[e] = make_uint2(l01,l23);
            }
        }
        __syncthreads();   // x2 ready for all waves

        // ---- GEMM2 MFMA: K=64, 3-pass ----
        f32x4 acc[4][2];
        #pragma unroll
        for (int mt=0;mt<4;++mt)
            #pragma unroll
            for (int nt=0;nt<2;++nt) {
                acc[mt][nt][0]=0.f; acc[mt][nt][1]=0.f;
                acc[mt][nt][2]=0.f; acc[mt][nt][3]=0.f;
            }
        #pragma unroll
        for (int ks=0; ks<2; ++ks) {
            s16x8 Ah[4], Al[4];
            #pragma unroll
            for (int mt=0;mt<4;++mt) {
                const int p = mt*16 + lr;
                const int e = (p*64 + ks*32 + g*8) ^ ((p&7)<<3);
                Ah[mt] = *(const s16x8*)&x2h[e];
                Al[mt] = *(const s16x8*)&x2l[e];
            }
            #pragma unroll
            for (int mt=0;mt<4;++mt)
                #pragma unroll
                for (int nt=0;nt<2;++nt) {
                    acc[mt][nt] = __builtin_amdgcn_mfma_f32_16x16x32_bf16(Ah[mt], Bh[nt][ks], acc[mt][nt], 0,0,0);
                    acc[mt][nt] = __builtin_amdgcn_mfma_f32_16x16x32_bf16(Al[mt], Bh[nt][ks], acc[mt][nt], 0,0,0);
                    acc[mt][nt] = __builtin_amdgcn_mfma_f32_16x16x32_bf16(Ah[mt], Bl[nt][ks], acc[mt][nt], 0,0,0);
                }
        }
        __syncthreads();   // reads done; next iter may overwrite

        // ---- epilogue: +t, per-voxel max/min, stats ----
        #pragma unroll
        for (int v=0; v<2; ++v) {
            #pragma unroll
            for (int nt=0; nt<2; ++nt) {
                const float tv = tvv[v][nt];
                const f32x4 qa = acc[2*v][nt], qb = acc[2*v+1][nt];
                float mx = fmaxf(fmaxf(fmaxf(qa[0],qa[1]), fmaxf(qa[2],qa[3])),
                                 fmaxf(fmaxf(qb[0],qb[1]), fmaxf(qb[2],qb[3])));
                float mn = fminf(fminf(fminf(qa[0],qa[1]), fminf(qa[2],qa[3])),
                                 fminf(fminf(qb[0],qb[1]), fminf(qb[2],qb[3])));
                mx = fmaxf(mx, __shfl_xor(mx,16)); mn = fminf(mn, __shfl_xor(mn,16));
                mx = fmaxf(mx, __shfl_xor(mx,32)); mn = fminf(mn, __shfl_xor(mn,32));
                if (lane < 16) {
                    const size_t o = (size_t)(vox0+v)*128 + w*32 + nt*16 + lr;
                    vmax2[o] = mx + tv; vmin2[o] = mn + tv;
                }
                float sl = 0.f, ql = 0.f;
                #pragma unroll
                for (int r=0;r<4;++r) {
                    float ea = qa[r] + tv, eb = qb[r] + tv;
                    sl += ea + eb;
                    ql = fmaf(ea,ea, fmaf(eb,eb, ql));
                }
                dsum[nt] += (double)sl; dsq[nt] += (double)ql;
            }
        }
    }
    #pragma unroll
    for (int nt=0; nt<2; ++nt) {
        double s = dsum[nt], q = dsq[nt];
        s += __shfl_xor(s,16); q += __shfl_xor(q,16);
        s += __shfl_xor(s,32); q += __shfl_xor(q,32);
        if (lane < 16) {
            atomicAdd(&sum2[w*32 + nt*16 + lr], s);
            atomicAdd(&sumsq2[w*32 + nt*16 + lr], q);
        }
    }
}

__global__ void k_fin2(const double* __restrict__ sum2, const double* __restrict__ sumsq2,
                       const float* __restrict__ g2, const float* __restrict__ b2,
                       float* __restrict__ sc2, float* __restrict__ sh2) {
    int c = threadIdx.x;
    if (c >= 128) return;
    double cnt = (double)NV * MP;
    double mu = sum2[c]/cnt;
    double var = sumsq2[c]/cnt - mu*mu;
    double rs = 1.0 / sqrt(var + 1e-3);
    double sc = (double)g2[c]*rs;
    sc2[c] = (float)sc;
    sh2[c] = (float)((double)b2[c] - mu*sc);
}

__global__ void k_out(const float* __restrict__ vmax2, const float* __restrict__ vmin2,
                      const float* __restrict__ sc2, const float* __restrict__ sh2,
                      float* __restrict__ out) {
    const int i = blockIdx.x*256 + threadIdx.x;   // < NV*32 exact
    const int c4 = (i & 31) << 2;
    const float4 mx = ((const float4*)vmax2)[i];
    const float4 mn = ((const float4*)vmin2)[i];
    const float4 sc = *(const float4*)&sc2[c4];
    const float4 sh = *(const float4*)&sh2[c4];
    float4 o;
    o.x = fmaxf(fmaf(sc.x>=0.f?mx.x:mn.x, sc.x, sh.x), 0.f);
    o.y = fmaxf(fmaf(sc.y>=0.f?mx.y:mn.y, sc.y, sh.y), 0.f);
    o.z = fmaxf(fmaf(sc.z>=0.f?mx.z:mn.z, sc.z, sh.z), 0.f);
    o.w = fmaxf(fmaf(sc.w>=0.f?mx.w:mn.w, sc.w, sh.w), 0.f);
    ((float4*)out)[i] = o;
}

extern "C" void kernel_launch(void* const* d_in, const int* in_sizes, int n_in,
                              void* d_out, int out_size, void* d_ws, size_t ws_size,
                              hipStream_t stream) {
    const float* feats = (const float*)d_in[0];
    const int*   npts  = (const int*)d_in[1];
    const int*   coors = (const int*)d_in[2];
    const float* W1    = (const float*)d_in[3];
    const float* g1    = (const float*)d_in[4];
    const float* b1    = (const float*)d_in[5];
    const float* W2    = (const float*)d_in[6];
    const float* g2    = (const float*)d_in[7];
    const float* b2    = (const float*)d_in[8];
    float* out = (float*)d_out;

    double* sum1   = (double*)d_ws;            // 64
    double* sumsq1 = sum1 + 64;                // 64
    double* sum2   = sumsq1 + 64;              // 128
    double* sumsq2 = sum2 + 128;               // 128 (384 doubles)
    float* fb = (float*)(sumsq2 + 128);
    float* vstat = fb;            fb += (size_t)NV*8;
    float* vmax1 = fb;            fb += (size_t)NV*64;
    float* vmin1 = fb;            fb += (size_t)NV*64;
    float* vmax2 = fb;            fb += (size_t)NV*128;
    float* vmin2 = fb;            fb += (size_t)NV*128;
    float* tbuf  = fb;            fb += (size_t)NV*128;
    float* sc1 = fb;              fb += 64;
    float* sh1 = fb;              fb += 64;
    float* sc2 = fb;              fb += 128;
    float* sh2 = fb;              fb += 128;

    hipMemsetAsync(d_ws, 0, 384*sizeof(double), stream);
    hipLaunchKernelGGL(k_gemm1, dim3(G1B), dim3(256), 0, stream,
                       feats, npts, coors, W1, vstat, vmax1, vmin1, sum1, sumsq1);
    hipLaunchKernelGGL(k_fin1, dim3(1), dim3(64), 0, stream,
                       sum1, sumsq1, g1, b1, sc1, sh1);
    hipLaunchKernelGGL(k_aggt, dim3(GAB), dim3(256), 0, stream,
                       vmax1, vmin1, sc1, sh1, W2, tbuf);
    hipLaunchKernelGGL(k_gemm2, dim3(G2B), dim3(256), 0, stream,
                       feats, npts, coors, vstat, W1, W2, sc1, sh1, tbuf,
                       vmax2, vmin2, sum2, sumsq2);
    hipLaunchKernelGGL(k_fin2, dim3(1), dim3(128), 0, stream,
                       sum2, sumsq2, g2, b2, sc2, sh2);
    hipLaunchKernelGGL(k_out, dim3(NV*32/256), dim3(256), 0, stream,
                       vmax2, vmin2, sc2, sh2, out);
}

// Round 10
// 299.674 us; speedup vs baseline: 1.3091x; 1.1023x over previous
//
#include <hip/hip_runtime.h>

#define NV 30000
#define MP 32

typedef short s16x8 __attribute__((ext_vector_type(8)));
typedef float f32x4 __attribute__((ext_vector_type(4)));

__device__ __forceinline__ unsigned short bf16h(float f) {
    unsigned int u = __float_as_uint(f);
    return (unsigned short)((u + 0x7FFFu + ((u >> 16) & 1u)) >> 16);
}
__device__ __forceinline__ float bf16f(unsigned short h) {
    return __uint_as_float(((unsigned int)h) << 16);
}
__device__ __forceinline__ unsigned int cvtpk(float a, float b) {
    unsigned int r;
    asm("v_cvt_pk_bf16_f32 %0, %1, %2" : "=v"(r) : "v"(a), "v"(b));
    return r;
}
// LDS write->read fence (intrinsic reads follow; no sched_barrier needed)
__device__ __forceinline__ void lgkm0() {
    asm volatile("s_waitcnt lgkmcnt(0)" ::: "memory");
}

// BN finalize math (shared by the redundant per-block recompute)
__device__ __forceinline__ void bn_fin(const double* sum, const double* sumsq,
                                       const float* gg, const float* bb, int c,
                                       float* sc, float* sh) {
    const double cnt = (double)NV * MP;
    double mu = sum[c]/cnt;
    double var = sumsq[c]/cnt - mu*mu;
    double rs = 1.0 / sqrt(var + 1e-3);
    double s = (double)gg[c]*rs;
    *sc = (float)s;
    *sh = (float)((double)bb[c] - mu*s);
}

// ---------------------------------------------------------------------------
// GEMM1: wave-per-voxel, fused voxstats, h1 via MFMA (bf16 3-pass).
// Grid 1875 x IT 4 x 4 waves = 30000 exact. Epilogue: LDS transpose
// (rotation-swizzled 16B blocks, 2 lanes/bank = free) -> lane-owns-channel
// in-register reduction. No shuffles, coalesced vmax1/vmin1 stores.
// launch_bounds(256,2): (256,4) caused 240 MB spill traffic (R8).
// ---------------------------------------------------------------------------
#define G1B 1875
#define G1IT 4
__global__ __launch_bounds__(256, 2) void k_gemm1(
    const float* __restrict__ feats, const int* __restrict__ npts,
    const int* __restrict__ coors, const float* __restrict__ W1,
    float* __restrict__ vstat,
    float* __restrict__ vmax1, float* __restrict__ vmin1,
    double* __restrict__ sum1, double* __restrict__ sumsq1)
{
    __shared__ unsigned short x1h[4][32*16], x1l[4][32*16];   // 4 KB
    __shared__ float hls[4][64*32];                           // 32 KB raw h1
    __shared__ float reds[4][64], redq[4][64];                // 2 KB

    const int t = threadIdx.x, wave = t>>6, lane = t&63;
    const int lr = lane&15, g = lane>>4, m = lane&31;

    // W1 A-frags: A[ch][k], ch = ct*16+lr, k = g*8+j (k>=13 -> 0)
    s16x8 Wh[4], Wl[4];
    #pragma unroll
    for (int ct=0; ct<4; ++ct)
        #pragma unroll
        for (int j=0;j<8;++j) {
            int k = g*8 + j;
            float v = (k < 13) ? W1[k*64 + ct*16 + lr] : 0.f;
            unsigned short h = bf16h(v);
            Wh[ct][j] = (short)h; Wl[ct][j] = (short)bf16h(v - bf16f(h));
        }
    float accs = 0.f, accq = 0.f;   // lane owns channel `lane`

    for (int it=0; it<G1IT; ++it) {
        const int v = (it*G1B + blockIdx.x)*4 + wave;   // < 30000 always
        if (lane < 32) {
            const int np = npts[v];
            const float fnp = (float)np;
            const float4 p = ((const float4*)feats)[(size_t)v*MP + m];
            const float msk = (m < np) ? 1.0f : 0.0f;
            float ux=p.x, uy=p.y, uz=p.z;
            float wx=p.x*msk, wy=p.y*msk, wz=p.z*msk;
            #pragma unroll
            for (int off=1; off<32; off<<=1) {
                ux += __shfl_xor(ux,off); uy += __shfl_xor(uy,off); uz += __shfl_xor(uz,off);
                wx += __shfl_xor(wx,off); wy += __shfl_xor(wy,off); wz += __shfl_xor(wz,off);
            }
            const float pmx=ux/fnp, pmy=uy/fnp, pmz=uz/fnp;
            const float vmx=wx/fnp, vmy=wy/fnp, vmz=wz/fnp;
            const float ddx=p.x-vmx, ddy=p.y-vmy, ddz=p.z-vmz;
            float d = sqrtf(ddx*ddx+ddy*ddy+ddz*ddz)*msk;
            #pragma unroll
            for (int off=1; off<32; off<<=1) d += __shfl_xor(d,off);
            const float md = d/fnp, dens = fnp/0.16f;
            if (m == 0) {
                float* o = vstat + (size_t)v*8;
                *(float4*)o       = make_float4(pmx,pmy,pmz,vmx);
                *(float4*)(o + 4) = make_float4(vmy,vmz,md,dens);
            }
            const float cx = (float)coors[v*4+3]*0.2f + 0.1f;
            const float cy = (float)coors[v*4+2]*0.2f - 39.9f;
            const float cz = (float)coors[v*4+1]*4.0f - 1.0f;
            float xv[16];
            xv[0]=p.x*msk; xv[1]=p.y*msk; xv[2]=p.z*msk; xv[3]=p.w*msk;
            xv[4]=(p.x-pmx)*msk; xv[5]=(p.y-pmy)*msk; xv[6]=(p.z-pmz)*msk;
            xv[7]=(p.x-cx)*msk; xv[8]=(p.y-cy)*msk; xv[9]=(p.z-cz)*msk;
            xv[10]=sqrtf(p.x*p.x+p.y*p.y+p.z*p.z)*msk;
            xv[11]=dens*msk; xv[12]=md*msk; xv[13]=0.f; xv[14]=0.f; xv[15]=0.f;
            unsigned int hu[8], lu[8];
            #pragma unroll
            for (int j=0;j<8;++j) {
                unsigned int hw = cvtpk(xv[2*j], xv[2*j+1]);
                float f0 = __uint_as_float(hw << 16);
                float f1 = __uint_as_float(hw & 0xffff0000u);
                lu[j] = cvtpk(xv[2*j]-f0, xv[2*j+1]-f1);
                hu[j] = hw;
            }
            const int base = m*16, sw = (m&7)<<3;
            *(uint4*)&x1h[wave][(base  ) ^ sw] = make_uint4(hu[0],hu[1],hu[2],hu[3]);
            *(uint4*)&x1h[wave][(base+8) ^ sw] = make_uint4(hu[4],hu[5],hu[6],hu[7]);
            *(uint4*)&x1l[wave][(base  ) ^ sw] = make_uint4(lu[0],lu[1],lu[2],lu[3]);
            *(uint4*)&x1l[wave][(base+8) ^ sw] = make_uint4(lu[4],lu[5],lu[6],lu[7]);
        }
        lgkm0();   // wave-private x1 RAW
        {
            const s16x8 zz = {0,0,0,0,0,0,0,0};
            s16x8 Bh[2], Bl[2];
            #pragma unroll
            for (int rg=0; rg<2; ++rg) {
                const int row = rg*16 + lr;
                if (g < 2) {
                    const int e = (row*16 + g*8) ^ ((row&7)<<3);
                    Bh[rg] = *(const s16x8*)&x1h[wave][e];
                    Bl[rg] = *(const s16x8*)&x1l[wave][e];
                } else { Bh[rg] = zz; Bl[rg] = zz; }
            }
            #pragma unroll
            for (int ct=0; ct<4; ++ct) {
                f32x4 h0; h0[0]=0.f;h0[1]=0.f;h0[2]=0.f;h0[3]=0.f;
                f32x4 h1v = h0;
                h0 = __builtin_amdgcn_mfma_f32_16x16x32_bf16(Wh[ct], Bh[0], h0, 0,0,0);
                h0 = __builtin_amdgcn_mfma_f32_16x16x32_bf16(Wl[ct], Bh[0], h0, 0,0,0);
                h0 = __builtin_amdgcn_mfma_f32_16x16x32_bf16(Wh[ct], Bl[0], h0, 0,0,0);
                h1v = __builtin_amdgcn_mfma_f32_16x16x32_bf16(Wh[ct], Bh[1], h1v, 0,0,0);
                h1v = __builtin_amdgcn_mfma_f32_16x16x32_bf16(Wl[ct], Bh[1], h1v, 0,0,0);
                h1v = __builtin_amdgcn_mfma_f32_16x16x32_bf16(Wh[ct], Bl[1], h1v, 0,0,0);
                // lane holds points {lr, 16+lr} of channels chb..chb+3 (raw h1)
                const int chb = ct*16 + g*4;
                #pragma unroll
                for (int r=0;r<4;++r) {
                    const int ch = chb + r;
                    float* row = &hls[wave][ch*32];
                    row[4*(((lr>>2)     + (ch&7)) & 7) + (lr&3)] = h0[r];
                    row[4*((4+(lr>>2)   + (ch&7)) & 7) + (lr&3)] = h1v[r];
                }
            }
        }
        lgkm0();   // wave-private hls RAW
        {
            // lane owns channel c = lane: read 32 points, reduce in-register
            const int c = lane, rb = c & 7;
            const float* row = &hls[wave][c*32];
            f32x4 v0 = *(const f32x4*)&row[4*((0+rb)&7)];
            float mx = fmaxf(fmaxf(v0[0],v0[1]), fmaxf(v0[2],v0[3]));
            float mn = fminf(fminf(v0[0],v0[1]), fminf(v0[2],v0[3]));
            float s  = (v0[0]+v0[1]) + (v0[2]+v0[3]);
            float q  = fmaf(v0[0],v0[0], fmaf(v0[1],v0[1], fmaf(v0[2],v0[2], v0[3]*v0[3])));
            #pragma unroll
            for (int j=1;j<8;++j) {
                f32x4 v4 = *(const f32x4*)&row[4*((j+rb)&7)];
                mx = fmaxf(mx, fmaxf(fmaxf(v4[0],v4[1]), fmaxf(v4[2],v4[3])));
                mn = fminf(mn, fminf(fminf(v4[0],v4[1]), fminf(v4[2],v4[3])));
                s += (v4[0]+v4[1]) + (v4[2]+v4[3]);
                q  = fmaf(v4[0],v4[0], fmaf(v4[1],v4[1], fmaf(v4[2],v4[2], fmaf(v4[3],v4[3], q))));
            }
            vmax1[(size_t)v*64 + c] = mx;
            vmin1[(size_t)v*64 + c] = mn;
            accs += s; accq += q;
        }
    }
    // stats: one LDS pass + 64 f64 atomics
    reds[wave][lane] = accs;
    redq[wave][lane] = accq;
    __syncthreads();
    if (t < 64) {
        atomicAdd(&sum1[t],   (double)(reds[0][t]+reds[1][t]+reds[2][t]+reds[3][t]));
        atomicAdd(&sumsq1[t], (double)(redq[0][t]+redq[1][t]+redq[2][t]+redq[3][t]));
    }
}

// t[v][c] = agg[v][0:64] @ W2[64:128][c]; sc1/sh1 recomputed per block (no fin1)
#define GAB 1875
__global__ __launch_bounds__(256) void k_aggt(
    const float* __restrict__ vmax1, const float* __restrict__ vmin1,
    const double* __restrict__ sum1, const double* __restrict__ sumsq1,
    const float* __restrict__ g1, const float* __restrict__ b1,
    const float* __restrict__ W2, float* __restrict__ tbuf)
{
    __shared__ float w2s[64][128];     // 32 KB, natural layout
    __shared__ float aggls[2][64];
    __shared__ float sc1s[64], sh1s[64];
    const int t = threadIdx.x;
    if (t < 64) bn_fin(sum1, sumsq1, g1, b1, t, &sc1s[t], &sh1s[t]);
    for (int i = t; i < 64*128; i += 256)
        ((float*)w2s)[i] = W2[64*128 + i];
    __syncthreads();
    const int v2 = t >> 7, c = t & 127;
    for (int it=0; it<8; ++it) {
        const int pair = it*GAB + blockIdx.x;   // < 15000 exact
        if (t < 128) {
            int vv = t >> 6, k = t & 63;
            float s = sc1s[k];
            size_t o = (size_t)(pair*2+vv)*64 + k;
            float v = (s >= 0.f) ? vmax1[o] : vmin1[o];
            aggls[vv][k] = fmaxf(fmaf(v, s, sh1s[k]), 0.f);
        }
        __syncthreads();
        float acc = 0.f;
        #pragma unroll 16
        for (int k=0; k<64; ++k)
            acc = fmaf(aggls[v2][k], w2s[k][c], acc);
        tbuf[(size_t)(pair*2+v2)*128 + c] = acc;
        __syncthreads();
    }
}

// ---------------------------------------------------------------------------
// GEMM2: 256 thr (4 waves), tile = 2 voxels (M=64) x N=128, K=64.
// Structure identical to R9 (measured); sc1/sh1 recomputed locally (no fin1).
// launch_bounds(256,2): (256,4) spills catastrophically (R8).
// ---------------------------------------------------------------------------
#define G2B 1875
#define G2IT 8
__global__ __launch_bounds__(256, 2) void k_gemm2(
    const float* __restrict__ feats, const int* __restrict__ npts,
    const int* __restrict__ coors, const float* __restrict__ vstat,
    const float* __restrict__ W1, const float* __restrict__ W2,
    const double* __restrict__ sum1, const double* __restrict__ sumsq1,
    const float* __restrict__ g1, const float* __restrict__ b1,
    const float* __restrict__ tbuf,
    float* __restrict__ vmax2, float* __restrict__ vmin2,
    double* __restrict__ sum2, double* __restrict__ sumsq2)
{
    __shared__ unsigned short x1h[64*16], x1l[64*16];   // 4 KB
    __shared__ unsigned short x2h[64*64], x2l[64*64];   // 16 KB
    __shared__ float sc1s[64], sh1s[64];

    const int t = threadIdx.x, w = t>>6, lane = t&63;
    const int lr = lane&15, g = lane>>4;

    if (t < 64) bn_fin(sum1, sumsq1, g1, b1, t, &sc1s[t], &sh1s[t]);
    __syncthreads();

    // W2a B-frags (wave's 32-col slice)
    s16x8 Bh[2][2], Bl[2][2];
    {
        const int col0 = w*32 + lr;
        #pragma unroll
        for (int nt=0; nt<2; ++nt)
            #pragma unroll
            for (int ks=0; ks<2; ++ks)
                #pragma unroll
                for (int j=0; j<8; ++j) {
                    float v = W2[(ks*32 + g*8 + j)*128 + col0 + nt*16];
                    unsigned short h = bf16h(v);
                    Bh[nt][ks][j] = (short)h;
                    Bl[nt][ks][j] = (short)bf16h(v - bf16f(h));
                }
    }
    // W1' A-frags (sc1 folded), all 4 ct per wave
    s16x8 Wh[4], Wl[4];
    float shr[4][4];
    #pragma unroll
    for (int ct=0; ct<4; ++ct) {
        const int ch = ct*16 + lr;
        const float scv = sc1s[ch];
        #pragma unroll
        for (int j=0; j<8; ++j) {
            int k = g*8 + j;
            float v = (k < 13) ? W1[k*64 + ch]*scv : 0.f;
            unsigned short h = bf16h(v);
            Wh[ct][j] = (short)h;
            Wl[ct][j] = (short)bf16h(v - bf16f(h));
        }
        #pragma unroll
        for (int r=0; r<4; ++r) shr[ct][r] = sh1s[ct*16 + g*4 + r];
    }

    const int myrow = w*16 + lr;
    const int swx = (myrow&7) << 3;
    double dsum[2] = {0.0,0.0}, dsq[2] = {0.0,0.0};

    for (int it=0; it<G2IT; ++it) {
        const int pair = it*G2B + blockIdx.x;   // < 15000 exact
        const int vox0 = pair*2;
        float tvv[2][2];
        #pragma unroll
        for (int v=0; v<2; ++v)
            #pragma unroll
            for (int nt=0; nt<2; ++nt)
                tvv[v][nt] = tbuf[(size_t)(vox0+v)*128 + w*32 + nt*16 + lr];

        // ---- stage x1 (wave-private rows, g==0 lanes) ----
        if (g == 0) {
            const int vox = vox0 + (myrow >> 5);
            const int np = npts[vox];
            const float cx = (float)coors[vox*4+3]*0.2f + 0.1f;
            const float cy = (float)coors[vox*4+2]*0.2f - 39.9f;
            const float cz = (float)coors[vox*4+1]*4.0f - 1.0f;
            const float4 vsa = *(const float4*)&vstat[(size_t)vox*8];
            const float4 vsb = *(const float4*)&vstat[(size_t)vox*8+4];
            const int m = myrow & 31;
            const float4 p = ((const float4*)feats)[(size_t)vox*MP + m];
            const float msk = (m < np) ? 1.0f : 0.0f;
            float xv[16];
            xv[0]=p.x*msk; xv[1]=p.y*msk; xv[2]=p.z*msk; xv[3]=p.w*msk;
            xv[4]=(p.x-vsa.x)*msk; xv[5]=(p.y-vsa.y)*msk; xv[6]=(p.z-vsa.z)*msk;
            xv[7]=(p.x-cx)*msk; xv[8]=(p.y-cy)*msk; xv[9]=(p.z-cz)*msk;
            xv[10]=sqrtf(p.x*p.x+p.y*p.y+p.z*p.z)*msk;
            xv[11]=vsb.w*msk; xv[12]=vsb.z*msk; xv[13]=0.f; xv[14]=0.f; xv[15]=0.f;
            unsigned int hu[8], lu[8];
            #pragma unroll
            for (int j=0;j<8;++j) {
                unsigned int hw = cvtpk(xv[2*j], xv[2*j+1]);
                float f0 = __uint_as_float(hw << 16);
                float f1 = __uint_as_float(hw & 0xffff0000u);
                lu[j] = cvtpk(xv[2*j]-f0, xv[2*j+1]-f1);
                hu[j] = hw;
            }
            const int base = myrow*16;
            *(uint4*)&x1h[(base  ) ^ swx] = make_uint4(hu[0],hu[1],hu[2],hu[3]);
            *(uint4*)&x1h[(base+8) ^ swx] = make_uint4(hu[4],hu[5],hu[6],hu[7]);
            *(uint4*)&x1l[(base  ) ^ swx] = make_uint4(lu[0],lu[1],lu[2],lu[3]);
            *(uint4*)&x1l[(base+8) ^ swx] = make_uint4(lu[4],lu[5],lu[6],lu[7]);
        }
        lgkm0();   // wave-private x1 RAW

        // ---- h1 phase: wave's 16 rows x 64 ch -> x2 ----
        {
            const s16x8 zz = {0,0,0,0,0,0,0,0};
            s16x8 xh = zz, xl = zz;
            if (g < 2) {
                const int be = (myrow*16 + g*8) ^ swx;
                xh = *(const s16x8*)&x1h[be];
                xl = *(const s16x8*)&x1l[be];
            }
            #pragma unroll
            for (int ct=0; ct<4; ++ct) {
                f32x4 hv;
                hv[0]=shr[ct][0]; hv[1]=shr[ct][1]; hv[2]=shr[ct][2]; hv[3]=shr[ct][3];
                hv = __builtin_amdgcn_mfma_f32_16x16x32_bf16(Wh[ct], xh, hv, 0,0,0);
                hv = __builtin_amdgcn_mfma_f32_16x16x32_bf16(Wl[ct], xh, hv, 0,0,0);
                hv = __builtin_amdgcn_mfma_f32_16x16x32_bf16(Wh[ct], xl, hv, 0,0,0);
                float a0 = fmaxf(hv[0],0.f), a1 = fmaxf(hv[1],0.f);
                float a2 = fmaxf(hv[2],0.f), a3 = fmaxf(hv[3],0.f);
                unsigned int h01 = cvtpk(a0,a1), h23 = cvtpk(a2,a3);
                float r0 = a0 - __uint_as_float(h01<<16);
                float r1 = a1 - __uint_as_float(h01 & 0xffff0000u);
                float r2 = a2 - __uint_as_float(h23<<16);
                float r3 = a3 - __uint_as_float(h23 & 0xffff0000u);
                unsigned int l01 = cvtpk(r0,r1), l23 = cvtpk(r2,r3);
                const int e = (myrow*64 + ct*16 + g*4) ^ swx;
                *(uint2*)&x2h[e] = make_uint2(h01,h23);
                *(uint2*)&x2l[e] = make_uint2(l01,l23);
            }
        }
        __syncthreads();   // x2 ready for all waves

        // ---- GEMM2 MFMA: K=64, 3-pass ----
        f32x4 acc[4][2];
        #pragma unroll
        for (int mt=0;mt<4;++mt)
            #pragma unroll
            for (int nt=0;nt<2;++nt) {
                acc[mt][nt][0]=0.f; acc[mt][nt][1]=0.f;
                acc[mt][nt][2]=0.f; acc[mt][nt][3]=0.f;
            }
        #pragma unroll
        for (int ks=0; ks<2; ++ks) {
            s16x8 Ah[4], Al[4];
            #pragma unroll
            for (int mt=0;mt<4;++mt) {
                const int p = mt*16 + lr;
                const int e = (p*64 + ks*32 + g*8) ^ ((p&7)<<3);
                Ah[mt] = *(const s16x8*)&x2h[e];
                Al[mt] = *(const s16x8*)&x2l[e];
            }
            #pragma unroll
            for (int mt=0;mt<4;++mt)
                #pragma unroll
                for (int nt=0;nt<2;++nt) {
                    acc[mt][nt] = __builtin_amdgcn_mfma_f32_16x16x32_bf16(Ah[mt], Bh[nt][ks], acc[mt][nt], 0,0,0);
                    acc[mt][nt] = __builtin_amdgcn_mfma_f32_16x16x32_bf16(Al[mt], Bh[nt][ks], acc[mt][nt], 0,0,0);
                    acc[mt][nt] = __builtin_amdgcn_mfma_f32_16x16x32_bf16(Ah[mt], Bl[nt][ks], acc[mt][nt], 0,0,0);
                }
        }
        __syncthreads();   // reads done; next iter may overwrite

        // ---- epilogue: +t, per-voxel max/min, stats ----
        #pragma unroll
        for (int v=0; v<2; ++v) {
            #pragma unroll
            for (int nt=0; nt<2; ++nt) {
                const float tv = tvv[v][nt];
                const f32x4 qa = acc[2*v][nt], qb = acc[2*v+1][nt];
                float mx = fmaxf(fmaxf(fmaxf(qa[0],qa[1]), fmaxf(qa[2],qa[3])),
                                 fmaxf(fmaxf(qb[0],qb[1]), fmaxf(qb[2],qb[3])));
                float mn = fminf(fminf(fminf(qa[0],qa[1]), fminf(qa[2],qa[3])),
                                 fminf(fminf(qb[0],qb[1]), fminf(qb[2],qb[3])));
                mx = fmaxf(mx, __shfl_xor(mx,16)); mn = fminf(mn, __shfl_xor(mn,16));
                mx = fmaxf(mx, __shfl_xor(mx,32)); mn = fminf(mn, __shfl_xor(mn,32));
                if (lane < 16) {
                    const size_t o = (size_t)(vox0+v)*128 + w*32 + nt*16 + lr;
                    vmax2[o] = mx + tv; vmin2[o] = mn + tv;
                }
                float sl = 0.f, ql = 0.f;
                #pragma unroll
                for (int r=0;r<4;++r) {
                    float ea = qa[r] + tv, eb = qb[r] + tv;
                    sl += ea + eb;
                    ql = fmaf(ea,ea, fmaf(eb,eb, ql));
                }
                dsum[nt] += (double)sl; dsq[nt] += (double)ql;
            }
        }
    }
    #pragma unroll
    for (int nt=0; nt<2; ++nt) {
        double s = dsum[nt], q = dsq[nt];
        s += __shfl_xor(s,16); q += __shfl_xor(q,16);
        s += __shfl_xor(s,32); q += __shfl_xor(q,32);
        if (lane < 16) {
            atomicAdd(&sum2[w*32 + nt*16 + lr], s);
            atomicAdd(&sumsq2[w*32 + nt*16 + lr], q);
        }
    }
}

// out = relu(affine(max-or-min)); sc2/sh2 recomputed per block (no fin2)
__global__ __launch_bounds__(256) void k_out(
    const float* __restrict__ vmax2, const float* __restrict__ vmin2,
    const double* __restrict__ sum2, const double* __restrict__ sumsq2,
    const float* __restrict__ g2, const float* __restrict__ b2,
    float* __restrict__ out)
{
    __shared__ float sc2s[128], sh2s[128];
    const int t = threadIdx.x;
    if (t < 128) bn_fin(sum2, sumsq2, g2, b2, t, &sc2s[t], &sh2s[t]);
    __syncthreads();
    const int i = blockIdx.x*256 + t;   // < NV*32 exact
    const int c4 = (i & 31) << 2;
    const float4 mx = ((const float4*)vmax2)[i];
    const float4 mn = ((const float4*)vmin2)[i];
    const float4 sc = *(const float4*)&sc2s[c4];
    const float4 sh = *(const float4*)&sh2s[c4];
    float4 o;
    o.x = fmaxf(fmaf(sc.x>=0.f?mx.x:mn.x, sc.x, sh.x), 0.f);
    o.y = fmaxf(fmaf(sc.y>=0.f?mx.y:mn.y, sc.y, sh.y), 0.f);
    o.z = fmaxf(fmaf(sc.z>=0.f?mx.z:mn.z, sc.z, sh.z), 0.f);
    o.w = fmaxf(fmaf(sc.w>=0.f?mx.w:mn.w, sc.w, sh.w), 0.f);
    ((float4*)out)[i] = o;
}

extern "C" void kernel_launch(void* const* d_in, const int* in_sizes, int n_in,
                              void* d_out, int out_size, void* d_ws, size_t ws_size,
                              hipStream_t stream) {
    const float* feats = (const float*)d_in[0];
    const int*   npts  = (const int*)d_in[1];
    const int*   coors = (const int*)d_in[2];
    const float* W1    = (const float*)d_in[3];
    const float* g1    = (const float*)d_in[4];
    const float* b1    = (const float*)d_in[5];
    const float* W2    = (const float*)d_in[6];
    const float* g2    = (const float*)d_in[7];
    const float* b2    = (const float*)d_in[8];
    float* out = (float*)d_out;

    double* sum1   = (double*)d_ws;            // 64
    double* sumsq1 = sum1 + 64;                // 64
    double* sum2   = sumsq1 + 64;              // 128
    double* sumsq2 = sum2 + 128;               // 128 (384 doubles)
    float* fb = (float*)(sumsq2 + 128);
    float* vstat = fb;            fb += (size_t)NV*8;
    float* vmax1 = fb;            fb += (size_t)NV*64;
    float* vmin1 = fb;            fb += (size_t)NV*64;
    float* vmax2 = fb;            fb += (size_t)NV*128;
    float* vmin2 = fb;            fb += (size_t)NV*128;
    float* tbuf  = fb;            fb += (size_t)NV*128;

    hipMemsetAsync(d_ws, 0, 384*sizeof(double), stream);
    hipLaunchKernelGGL(k_gemm1, dim3(G1B), dim3(256), 0, stream,
                       feats, npts, coors, W1, vstat, vmax1, vmin1, sum1, sumsq1);
    hipLaunchKernelGGL(k_aggt, dim3(GAB), dim3(256), 0, stream,
                       vmax1, vmin1, sum1, sumsq1, g1, b1, W2, tbuf);
    hipLaunchKernelGGL(k_gemm2, dim3(G2B), dim3(256), 0, stream,
                       feats, npts, coors, vstat, W1, W2, sum1, sumsq1, g1, b1,
                       tbuf, vmax2, vmin2, sum2, sumsq2);
    hipLaunchKernelGGL(k_out, dim3(NV*32/256), dim3(256), 0, stream,
                       vmax2, vmin2, sum2, sumsq2, g2, b2, out);
}

// Round 11
// 297.457 us; speedup vs baseline: 1.3189x; 1.0075x over previous
//
#include <hip/hip_runtime.h>

#define NV 30000
#define MP 32

typedef short s16x8 __attribute__((ext_vector_type(8)));
typedef float f32x4 __attribute__((ext_vector_type(4)));

__device__ __forceinline__ unsigned short bf16h(float f) {
    unsigned int u = __float_as_uint(f);
    return (unsigned short)((u + 0x7FFFu + ((u >> 16) & 1u)) >> 16);
}
__device__ __forceinline__ float bf16f(unsigned short h) {
    return __uint_as_float(((unsigned int)h) << 16);
}
__device__ __forceinline__ unsigned int cvtpk(float a, float b) {
    unsigned int r;
    asm("v_cvt_pk_bf16_f32 %0, %1, %2" : "=v"(r) : "v"(a), "v"(b));
    return r;
}
// LDS write->read fence, wave-local
__device__ __forceinline__ void lgkm0() {
    asm volatile("s_waitcnt lgkmcnt(0)" ::: "memory");
}
// block barrier WITHOUT vmcnt drain: LDS-visibility only; global loads stay
// in flight across it (T4; hipcc's __syncthreads drains vmcnt(0) — m97 stall)
__device__ __forceinline__ void lds_barrier() {
    asm volatile("s_waitcnt lgkmcnt(0)\ns_barrier" ::: "memory");
}

// BN finalize math (redundant per-block recompute; no fin kernels)
__device__ __forceinline__ void bn_fin(const double* sum, const double* sumsq,
                                       const float* gg, const float* bb, int c,
                                       float* sc, float* sh) {
    const double cnt = (double)NV * MP;
    double mu = sum[c]/cnt;
    double var = sumsq[c]/cnt - mu*mu;
    double rs = 1.0 / sqrt(var + 1e-3);
    double s = (double)gg[c]*rs;
    *sc = (float)s;
    *sh = (float)((double)bb[c] - mu*s);
}

// ---------------------------------------------------------------------------
// GEMM1: wave-per-voxel, fused voxstats, h1 via MFMA (bf16 3-pass).
// UNCHANGED from R10 measured build (299.7 total).
// ---------------------------------------------------------------------------
#define G1B 1875
#define G1IT 4
__global__ __launch_bounds__(256, 2) void k_gemm1(
    const float* __restrict__ feats, const int* __restrict__ npts,
    const int* __restrict__ coors, const float* __restrict__ W1,
    float* __restrict__ vstat,
    float* __restrict__ vmax1, float* __restrict__ vmin1,
    double* __restrict__ sum1, double* __restrict__ sumsq1)
{
    __shared__ unsigned short x1h[4][32*16], x1l[4][32*16];   // 4 KB
    __shared__ float hls[4][64*32];                           // 32 KB raw h1
    __shared__ float reds[4][64], redq[4][64];                // 2 KB

    const int t = threadIdx.x, wave = t>>6, lane = t&63;
    const int lr = lane&15, g = lane>>4, m = lane&31;

    s16x8 Wh[4], Wl[4];
    #pragma unroll
    for (int ct=0; ct<4; ++ct)
        #pragma unroll
        for (int j=0;j<8;++j) {
            int k = g*8 + j;
            float v = (k < 13) ? W1[k*64 + ct*16 + lr] : 0.f;
            unsigned short h = bf16h(v);
            Wh[ct][j] = (short)h; Wl[ct][j] = (short)bf16h(v - bf16f(h));
        }
    float accs = 0.f, accq = 0.f;   // lane owns channel `lane`

    for (int it=0; it<G1IT; ++it) {
        const int v = (it*G1B + blockIdx.x)*4 + wave;   // < 30000 always
        if (lane < 32) {
            const int np = npts[v];
            const float fnp = (float)np;
            const float4 p = ((const float4*)feats)[(size_t)v*MP + m];
            const float msk = (m < np) ? 1.0f : 0.0f;
            float ux=p.x, uy=p.y, uz=p.z;
            float wx=p.x*msk, wy=p.y*msk, wz=p.z*msk;
            #pragma unroll
            for (int off=1; off<32; off<<=1) {
                ux += __shfl_xor(ux,off); uy += __shfl_xor(uy,off); uz += __shfl_xor(uz,off);
                wx += __shfl_xor(wx,off); wy += __shfl_xor(wy,off); wz += __shfl_xor(wz,off);
            }
            const float pmx=ux/fnp, pmy=uy/fnp, pmz=uz/fnp;
            const float vmx=wx/fnp, vmy=wy/fnp, vmz=wz/fnp;
            const float ddx=p.x-vmx, ddy=p.y-vmy, ddz=p.z-vmz;
            float d = sqrtf(ddx*ddx+ddy*ddy+ddz*ddz)*msk;
            #pragma unroll
            for (int off=1; off<32; off<<=1) d += __shfl_xor(d,off);
            const float md = d/fnp, dens = fnp/0.16f;
            if (m == 0) {
                float* o = vstat + (size_t)v*8;
                *(float4*)o       = make_float4(pmx,pmy,pmz,vmx);
                *(float4*)(o + 4) = make_float4(vmy,vmz,md,dens);
            }
            const float cx = (float)coors[v*4+3]*0.2f + 0.1f;
            const float cy = (float)coors[v*4+2]*0.2f - 39.9f;
            const float cz = (float)coors[v*4+1]*4.0f - 1.0f;
            float xv[16];
            xv[0]=p.x*msk; xv[1]=p.y*msk; xv[2]=p.z*msk; xv[3]=p.w*msk;
            xv[4]=(p.x-pmx)*msk; xv[5]=(p.y-pmy)*msk; xv[6]=(p.z-pmz)*msk;
            xv[7]=(p.x-cx)*msk; xv[8]=(p.y-cy)*msk; xv[9]=(p.z-cz)*msk;
            xv[10]=sqrtf(p.x*p.x+p.y*p.y+p.z*p.z)*msk;
            xv[11]=dens*msk; xv[12]=md*msk; xv[13]=0.f; xv[14]=0.f; xv[15]=0.f;
            unsigned int hu[8], lu[8];
            #pragma unroll
            for (int j=0;j<8;++j) {
                unsigned int hw = cvtpk(xv[2*j], xv[2*j+1]);
                float f0 = __uint_as_float(hw << 16);
                float f1 = __uint_as_float(hw & 0xffff0000u);
                lu[j] = cvtpk(xv[2*j]-f0, xv[2*j+1]-f1);
                hu[j] = hw;
            }
            const int base = m*16, sw = (m&7)<<3;
            *(uint4*)&x1h[wave][(base  ) ^ sw] = make_uint4(hu[0],hu[1],hu[2],hu[3]);
            *(uint4*)&x1h[wave][(base+8) ^ sw] = make_uint4(hu[4],hu[5],hu[6],hu[7]);
            *(uint4*)&x1l[wave][(base  ) ^ sw] = make_uint4(lu[0],lu[1],lu[2],lu[3]);
            *(uint4*)&x1l[wave][(base+8) ^ sw] = make_uint4(lu[4],lu[5],lu[6],lu[7]);
        }
        lgkm0();   // wave-private x1 RAW
        {
            const s16x8 zz = {0,0,0,0,0,0,0,0};
            s16x8 Bh[2], Bl[2];
            #pragma unroll
            for (int rg=0; rg<2; ++rg) {
                const int row = rg*16 + lr;
                if (g < 2) {
                    const int e = (row*16 + g*8) ^ ((row&7)<<3);
                    Bh[rg] = *(const s16x8*)&x1h[wave][e];
                    Bl[rg] = *(const s16x8*)&x1l[wave][e];
                } else { Bh[rg] = zz; Bl[rg] = zz; }
            }
            #pragma unroll
            for (int ct=0; ct<4; ++ct) {
                f32x4 h0; h0[0]=0.f;h0[1]=0.f;h0[2]=0.f;h0[3]=0.f;
                f32x4 h1v = h0;
                h0 = __builtin_amdgcn_mfma_f32_16x16x32_bf16(Wh[ct], Bh[0], h0, 0,0,0);
                h0 = __builtin_amdgcn_mfma_f32_16x16x32_bf16(Wl[ct], Bh[0], h0, 0,0,0);
                h0 = __builtin_amdgcn_mfma_f32_16x16x32_bf16(Wh[ct], Bl[0], h0, 0,0,0);
                h1v = __builtin_amdgcn_mfma_f32_16x16x32_bf16(Wh[ct], Bh[1], h1v, 0,0,0);
                h1v = __builtin_amdgcn_mfma_f32_16x16x32_bf16(Wl[ct], Bh[1], h1v, 0,0,0);
                h1v = __builtin_amdgcn_mfma_f32_16x16x32_bf16(Wh[ct], Bl[1], h1v, 0,0,0);
                const int chb = ct*16 + g*4;
                #pragma unroll
                for (int r=0;r<4;++r) {
                    const int ch = chb + r;
                    float* row = &hls[wave][ch*32];
                    row[4*(((lr>>2)     + (ch&7)) & 7) + (lr&3)] = h0[r];
                    row[4*((4+(lr>>2)   + (ch&7)) & 7) + (lr&3)] = h1v[r];
                }
            }
        }
        lgkm0();   // wave-private hls RAW
        {
            const int c = lane, rb = c & 7;
            const float* row = &hls[wave][c*32];
            f32x4 v0 = *(const f32x4*)&row[4*((0+rb)&7)];
            float mx = fmaxf(fmaxf(v0[0],v0[1]), fmaxf(v0[2],v0[3]));
            float mn = fminf(fminf(v0[0],v0[1]), fminf(v0[2],v0[3]));
            float s  = (v0[0]+v0[1]) + (v0[2]+v0[3]);
            float q  = fmaf(v0[0],v0[0], fmaf(v0[1],v0[1], fmaf(v0[2],v0[2], v0[3]*v0[3])));
            #pragma unroll
            for (int j=1;j<8;++j) {
                f32x4 v4 = *(const f32x4*)&row[4*((j+rb)&7)];
                mx = fmaxf(mx, fmaxf(fmaxf(v4[0],v4[1]), fmaxf(v4[2],v4[3])));
                mn = fminf(mn, fminf(fminf(v4[0],v4[1]), fminf(v4[2],v4[3])));
                s += (v4[0]+v4[1]) + (v4[2]+v4[3]);
                q  = fmaf(v4[0],v4[0], fmaf(v4[1],v4[1], fmaf(v4[2],v4[2], fmaf(v4[3],v4[3], q))));
            }
            vmax1[(size_t)v*64 + c] = mx;
            vmin1[(size_t)v*64 + c] = mn;
            accs += s; accq += q;
        }
    }
    reds[wave][lane] = accs;
    redq[wave][lane] = accq;
    __syncthreads();
    if (t < 64) {
        atomicAdd(&sum1[t],   (double)(reds[0][t]+reds[1][t]+reds[2][t]+reds[3][t]));
        atomicAdd(&sumsq1[t], (double)(redq[0][t]+redq[1][t]+redq[2][t]+redq[3][t]));
    }
}

// t[v][c] = agg[v][0:64] @ W2[64:128][c]; UNCHANGED from R10 measured build
#define GAB 1875
__global__ __launch_bounds__(256) void k_aggt(
    const float* __restrict__ vmax1, const float* __restrict__ vmin1,
    const double* __restrict__ sum1, const double* __restrict__ sumsq1,
    const float* __restrict__ g1, const float* __restrict__ b1,
    const float* __restrict__ W2, float* __restrict__ tbuf)
{
    __shared__ float w2s[64][128];
    __shared__ float aggls[2][64];
    __shared__ float sc1s[64], sh1s[64];
    const int t = threadIdx.x;
    if (t < 64) bn_fin(sum1, sumsq1, g1, b1, t, &sc1s[t], &sh1s[t]);
    for (int i = t; i < 64*128; i += 256)
        ((float*)w2s)[i] = W2[64*128 + i];
    __syncthreads();
    const int v2 = t >> 7, c = t & 127;
    for (int it=0; it<8; ++it) {
        const int pair = it*GAB + blockIdx.x;
        if (t < 128) {
            int vv = t >> 6, k = t & 63;
            float s = sc1s[k];
            size_t o = (size_t)(pair*2+vv)*64 + k;
            float v = (s >= 0.f) ? vmax1[o] : vmin1[o];
            aggls[vv][k] = fmaxf(fmaf(v, s, sh1s[k]), 0.f);
        }
        __syncthreads();
        float acc = 0.f;
        #pragma unroll 16
        for (int k=0; k<64; ++k)
            acc = fmaf(aggls[v2][k], w2s[k][c], acc);
        tbuf[(size_t)(pair*2+v2)*128 + c] = acc;
        __syncthreads();
    }
}

// ---------------------------------------------------------------------------
// GEMM2 v2: 256 thr (4 waves), BATCH-2 pairs per phase (4 voxels, 128 rows).
// Wave w stages voxel vox0+w (32 lanes, wave-uniform scalars, coalesced),
// computes h1 for rows w*32..+32 (24 MFMA), then GEMM N-slice w*32 over all
// 128 rows (96 MFMA). 8 lds_barriers (no vmcnt drain) per block vs R10's 16
// full __syncthreads. Next-batch feats row + tbuf prefetched under h1+GEMM.
// Grid 1875 x 4 batches x 2 pairs = 15000 exact.
// launch_bounds(256,2): (256,4) spills catastrophically (R8).
// ---------------------------------------------------------------------------
#define G2B 1875
#define G2BT 4
__global__ __launch_bounds__(256, 2) void k_gemm2(
    const float* __restrict__ feats, const int* __restrict__ npts,
    const int* __restrict__ coors, const float* __restrict__ vstat,
    const float* __restrict__ W1, const float* __restrict__ W2,
    const double* __restrict__ sum1, const double* __restrict__ sumsq1,
    const float* __restrict__ g1, const float* __restrict__ b1,
    const float* __restrict__ tbuf,
    float* __restrict__ vmax2, float* __restrict__ vmin2,
    double* __restrict__ sum2, double* __restrict__ sumsq2)
{
    __shared__ unsigned short x1h[128*16], x1l[128*16];   // 8 KB
    __shared__ unsigned short x2h[128*64], x2l[128*64];   // 32 KB
    __shared__ float sc1s[64], sh1s[64];

    const int t = threadIdx.x, w = t>>6, lane = t&63;
    const int lr = lane&15, g = lane>>4, m = lane&31;

    if (t < 64) bn_fin(sum1, sumsq1, g1, b1, t, &sc1s[t], &sh1s[t]);
    __syncthreads();

    // W2a B-frags (wave's 32-col slice)
    s16x8 Bh[2][2], Bl[2][2];
    {
        const int col0 = w*32 + lr;
        #pragma unroll
        for (int nt=0; nt<2; ++nt)
            #pragma unroll
            for (int ks=0; ks<2; ++ks)
                #pragma unroll
                for (int j=0; j<8; ++j) {
                    float v = W2[(ks*32 + g*8 + j)*128 + col0 + nt*16];
                    unsigned short h = bf16h(v);
                    Bh[nt][ks][j] = (short)h;
                    Bl[nt][ks][j] = (short)bf16h(v - bf16f(h));
                }
    }
    // W1' A-frags (sc1 folded), all 4 ct per wave
    s16x8 Wh[4], Wl[4];
    float shr[4][4];
    #pragma unroll
    for (int ct=0; ct<4; ++ct) {
        const int ch = ct*16 + lr;
        const float scv = sc1s[ch];
        #pragma unroll
        for (int j=0; j<8; ++j) {
            int k = g*8 + j;
            float v = (k < 13) ? W1[k*64 + ch]*scv : 0.f;
            unsigned short h = bf16h(v);
            Wh[ct][j] = (short)h;
            Wl[ct][j] = (short)bf16h(v - bf16f(h));
        }
        #pragma unroll
        for (int r=0; r<4; ++r) shr[ct][r] = sh1s[ct*16 + g*4 + r];
    }

    double dsum[2] = {0.0,0.0}, dsq[2] = {0.0,0.0};

    // ---- prologue prefetch: batch 0 ----
    int vox0 = 4*blockIdx.x;
    float4 ptC, ptN;
    float tC[4][2], tN[4][2];
    if (lane < 32)
        ptC = ((const float4*)feats)[(size_t)(vox0 + w)*MP + m];
    #pragma unroll
    for (int u=0; u<4; ++u)
        #pragma unroll
        for (int nt=0; nt<2; ++nt)
            tC[u][nt] = tbuf[(size_t)(vox0+u)*128 + w*32 + nt*16 + lr];

    for (int b=0; b<G2BT; ++b) {
        // ---- stage x1: wave w stages voxel vox0+w (32 lanes, 1 row each) ----
        if (lane < 32) {
            const int vox = vox0 + w;                 // wave-uniform
            const int np = npts[vox];
            const int4 co = *(const int4*)&coors[vox*4];
            const float cx = (float)co.w*0.2f + 0.1f;
            const float cy = (float)co.z*0.2f - 39.9f;
            const float cz = (float)co.y*4.0f - 1.0f;
            const float4 vsa = *(const float4*)&vstat[(size_t)vox*8];
            const float4 vsb = *(const float4*)&vstat[(size_t)vox*8+4];
            const float4 p = ptC;
            const float msk = (m < np) ? 1.0f : 0.0f;
            float xv[16];
            xv[0]=p.x*msk; xv[1]=p.y*msk; xv[2]=p.z*msk; xv[3]=p.w*msk;
            xv[4]=(p.x-vsa.x)*msk; xv[5]=(p.y-vsa.y)*msk; xv[6]=(p.z-vsa.z)*msk;
            xv[7]=(p.x-cx)*msk; xv[8]=(p.y-cy)*msk; xv[9]=(p.z-cz)*msk;
            xv[10]=sqrtf(p.x*p.x+p.y*p.y+p.z*p.z)*msk;
            xv[11]=vsb.w*msk; xv[12]=vsb.z*msk; xv[13]=0.f; xv[14]=0.f; xv[15]=0.f;
            unsigned int hu[8], lu[8];
            #pragma unroll
            for (int j=0;j<8;++j) {
                unsigned int hw = cvtpk(xv[2*j], xv[2*j+1]);
                float f0 = __uint_as_float(hw << 16);
                float f1 = __uint_as_float(hw & 0xffff0000u);
                lu[j] = cvtpk(xv[2*j]-f0, xv[2*j+1]-f1);
                hu[j] = hw;
            }
            const int srow = w*32 + m;
            const int base = srow*16, sw = (srow&7)<<3;
            *(uint4*)&x1h[(base  ) ^ sw] = make_uint4(hu[0],hu[1],hu[2],hu[3]);
            *(uint4*)&x1h[(base+8) ^ sw] = make_uint4(hu[4],hu[5],hu[6],hu[7]);
            *(uint4*)&x1l[(base  ) ^ sw] = make_uint4(lu[0],lu[1],lu[2],lu[3]);
            *(uint4*)&x1l[(base+8) ^ sw] = make_uint4(lu[4],lu[5],lu[6],lu[7]);
        }
        // ---- issue next-batch prefetch (lands under h1 + GEMM) ----
        if (b < G2BT-1) {
            const int vox0n = vox0 + 4*G2B;
            if (lane < 32)
                ptN = ((const float4*)feats)[(size_t)(vox0n + w)*MP + m];
            #pragma unroll
            for (int u=0; u<4; ++u)
                #pragma unroll
                for (int nt=0; nt<2; ++nt)
                    tN[u][nt] = tbuf[(size_t)(vox0n+u)*128 + w*32 + nt*16 + lr];
        }
        lgkm0();   // wave-private x1 RAW (wave stages its own rows)

        // ---- h1 phase: wave's 32 rows (2 row-groups) x 64 ch -> x2 ----
        {
            const s16x8 zz = {0,0,0,0,0,0,0,0};
            #pragma unroll
            for (int rg=0; rg<2; ++rg) {
                const int brow = w*32 + rg*16 + lr;
                s16x8 xh = zz, xl = zz;
                if (g < 2) {
                    const int e = (brow*16 + g*8) ^ ((brow&7)<<3);
                    xh = *(const s16x8*)&x1h[e];
                    xl = *(const s16x8*)&x1l[e];
                }
                #pragma unroll
                for (int ct=0; ct<4; ++ct) {
                    f32x4 hv;
                    hv[0]=shr[ct][0]; hv[1]=shr[ct][1]; hv[2]=shr[ct][2]; hv[3]=shr[ct][3];
                    hv = __builtin_amdgcn_mfma_f32_16x16x32_bf16(Wh[ct], xh, hv, 0,0,0);
                    hv = __builtin_amdgcn_mfma_f32_16x16x32_bf16(Wl[ct], xh, hv, 0,0,0);
                    hv = __builtin_amdgcn_mfma_f32_16x16x32_bf16(Wh[ct], xl, hv, 0,0,0);
                    float a0 = fmaxf(hv[0],0.f), a1 = fmaxf(hv[1],0.f);
                    float a2 = fmaxf(hv[2],0.f), a3 = fmaxf(hv[3],0.f);
                    unsigned int h01 = cvtpk(a0,a1), h23 = cvtpk(a2,a3);
                    float r0 = a0 - __uint_as_float(h01<<16);
                    float r1 = a1 - __uint_as_float(h01 & 0xffff0000u);
                    float r2 = a2 - __uint_as_float(h23<<16);
                    float r3 = a3 - __uint_as_float(h23 & 0xffff0000u);
                    unsigned int l01 = cvtpk(r0,r1), l23 = cvtpk(r2,r3);
                    const int p2 = w*32 + rg*16 + lr;
                    const int e = (p2*64 + ct*16 + g*4) ^ ((p2&7)<<3);
                    *(uint2*)&x2h[e] = make_uint2(h01,h23);
                    *(uint2*)&x2l[e] = make_uint2(l01,l23);
                }
            }
        }
        lds_barrier();   // x2 visible to all waves; global prefetch stays in flight

        // ---- GEMM: 128 rows x wave's 32 cols, K=64, 3-pass ----
        f32x4 acc[8][2];
        #pragma unroll
        for (int mt=0;mt<8;++mt)
            #pragma unroll
            for (int nt=0;nt<2;++nt) {
                acc[mt][nt][0]=0.f; acc[mt][nt][1]=0.f;
                acc[mt][nt][2]=0.f; acc[mt][nt][3]=0.f;
            }
        #pragma unroll
        for (int ks=0; ks<2; ++ks) {
            #pragma unroll
            for (int mt=0;mt<8;++mt) {
                const int p2 = mt*16 + lr;
                const int e = (p2*64 + ks*32 + g*8) ^ ((p2&7)<<3);
                const s16x8 Ah = *(const s16x8*)&x2h[e];
                const s16x8 Al = *(const s16x8*)&x2l[e];
                #pragma unroll
                for (int nt=0;nt<2;++nt) {
                    acc[mt][nt] = __builtin_amdgcn_mfma_f32_16x16x32_bf16(Ah, Bh[nt][ks], acc[mt][nt], 0,0,0);
                    acc[mt][nt] = __builtin_amdgcn_mfma_f32_16x16x32_bf16(Al, Bh[nt][ks], acc[mt][nt], 0,0,0);
                    acc[mt][nt] = __builtin_amdgcn_mfma_f32_16x16x32_bf16(Ah, Bl[nt][ks], acc[mt][nt], 0,0,0);
                }
            }
        }
        lds_barrier();   // x2/x1 reads done; next batch may overwrite

        // ---- epilogue: +t, per-voxel max/min, stats (4 voxels) ----
        #pragma unroll
        for (int u=0; u<4; ++u) {
            #pragma unroll
            for (int nt=0; nt<2; ++nt) {
                const float tv = tC[u][nt];
                const f32x4 qa = acc[2*u][nt], qb = acc[2*u+1][nt];
                float mx = fmaxf(fmaxf(fmaxf(qa[0],qa[1]), fmaxf(qa[2],qa[3])),
                                 fmaxf(fmaxf(qb[0],qb[1]), fmaxf(qb[2],qb[3])));
                float mn = fminf(fminf(fminf(qa[0],qa[1]), fminf(qa[2],qa[3])),
                                 fminf(fminf(qb[0],qb[1]), fminf(qb[2],qb[3])));
                mx = fmaxf(mx, __shfl_xor(mx,16)); mn = fminf(mn, __shfl_xor(mn,16));
                mx = fmaxf(mx, __shfl_xor(mx,32)); mn = fminf(mn, __shfl_xor(mn,32));
                if (lane < 16) {
                    const size_t o = (size_t)(vox0+u)*128 + w*32 + nt*16 + lr;
                    vmax2[o] = mx + tv; vmin2[o] = mn + tv;
                }
                float sl = 0.f, ql = 0.f;
                #pragma unroll
                for (int r=0;r<4;++r) {
                    float ea = qa[r] + tv, eb = qb[r] + tv;
                    sl += ea + eb;
                    ql = fmaf(ea,ea, fmaf(eb,eb, ql));
                }
                dsum[nt] += (double)sl; dsq[nt] += (double)ql;
            }
        }
        // rotate prefetch
        ptC = ptN;
        #pragma unroll
        for (int u=0; u<4; ++u)
            #pragma unroll
            for (int nt=0; nt<2; ++nt)
                tC[u][nt] = tN[u][nt];
        vox0 += 4*G2B;
    }
    #pragma unroll
    for (int nt=0; nt<2; ++nt) {
        double s = dsum[nt], q = dsq[nt];
        s += __shfl_xor(s,16); q += __shfl_xor(q,16);
        s += __shfl_xor(s,32); q += __shfl_xor(q,32);
        if (lane < 16) {
            atomicAdd(&sum2[w*32 + nt*16 + lr], s);
            atomicAdd(&sumsq2[w*32 + nt*16 + lr], q);
        }
    }
}

// out = relu(affine(max-or-min)); UNCHANGED from R10 measured build
__global__ __launch_bounds__(256) void k_out(
    const float* __restrict__ vmax2, const float* __restrict__ vmin2,
    const double* __restrict__ sum2, const double* __restrict__ sumsq2,
    const float* __restrict__ g2, const float* __restrict__ b2,
    float* __restrict__ out)
{
    __shared__ float sc2s[128], sh2s[128];
    const int t = threadIdx.x;
    if (t < 128) bn_fin(sum2, sumsq2, g2, b2, t, &sc2s[t], &sh2s[t]);
    __syncthreads();
    const int i = blockIdx.x*256 + t;   // < NV*32 exact
    const int c4 = (i & 31) << 2;
    const float4 mx = ((const float4*)vmax2)[i];
    const float4 mn = ((const float4*)vmin2)[i];
    const float4 sc = *(const float4*)&sc2s[c4];
    const float4 sh = *(const float4*)&sh2s[c4];
    float4 o;
    o.x = fmaxf(fmaf(sc.x>=0.f?mx.x:mn.x, sc.x, sh.x), 0.f);
    o.y = fmaxf(fmaf(sc.y>=0.f?mx.y:mn.y, sc.y, sh.y), 0.f);
    o.z = fmaxf(fmaf(sc.z>=0.f?mx.z:mn.z, sc.z, sh.z), 0.f);
    o.w = fmaxf(fmaf(sc.w>=0.f?mx.w:mn.w, sc.w, sh.w), 0.f);
    ((float4*)out)[i] = o;
}

extern "C" void kernel_launch(void* const* d_in, const int* in_sizes, int n_in,
                              void* d_out, int out_size, void* d_ws, size_t ws_size,
                              hipStream_t stream) {
    const float* feats = (const float*)d_in[0];
    const int*   npts  = (const int*)d_in[1];
    const int*   coors = (const int*)d_in[2];
    const float* W1    = (const float*)d_in[3];
    const float* g1    = (const float*)d_in[4];
    const float* b1    = (const float*)d_in[5];
    const float* W2    = (const float*)d_in[6];
    const float* g2    = (const float*)d_in[7];
    const float* b2    = (const float*)d_in[8];
    float* out = (float*)d_out;

    double* sum1   = (double*)d_ws;            // 64
    double* sumsq1 = sum1 + 64;                // 64
    double* sum2   = sumsq1 + 64;              // 128
    double* sumsq2 = sum2 + 128;               // 128 (384 doubles)
    float* fb = (float*)(sumsq2 + 128);
    float* vstat = fb;            fb += (size_t)NV*8;
    float* vmax1 = fb;            fb += (size_t)NV*64;
    float* vmin1 = fb;            fb += (size_t)NV*64;
    float* vmax2 = fb;            fb += (size_t)NV*128;
    float* vmin2 = fb;            fb += (size_t)NV*128;
    float* tbuf  = fb;            fb += (size_t)NV*128;

    hipMemsetAsync(d_ws, 0, 384*sizeof(double), stream);
    hipLaunchKernelGGL(k_gemm1, dim3(G1B), dim3(256), 0, stream,
                       feats, npts, coors, W1, vstat, vmax1, vmin1, sum1, sumsq1);
    hipLaunchKernelGGL(k_aggt, dim3(GAB), dim3(256), 0, stream,
                       vmax1, vmin1, sum1, sumsq1, g1, b1, W2, tbuf);
    hipLaunchKernelGGL(k_gemm2, dim3(G2B), dim3(256), 0, stream,
                       feats, npts, coors, vstat, W1, W2, sum1, sumsq1, g1, b1,
                       tbuf, vmax2, vmin2, sum2, sumsq2);
    hipLaunchKernelGGL(k_out, dim3(NV*32/256), dim3(256), 0, stream,
                       vmax2, vmin2, sum2, sumsq2, g2, b2, out);
}